// Round 7
// baseline (561.909 us; speedup 1.0000x reference)
//
#include <hip/hip_runtime.h>

#define WAVE 64
#define OW 256    // hidden width
#define LDA1 96   // padded layer-1 K (67 -> 96, zero pad)

typedef short bf16x8 __attribute__((ext_vector_type(8)));
typedef float f32x4  __attribute__((ext_vector_type(4)));

__device__ __forceinline__ unsigned short f2bf(float f) {   // RNE fp32 -> bf16
    unsigned int u = __float_as_uint(f);
    u = (u + 0x7FFF + ((u >> 16) & 1)) >> 16;
    return (unsigned short)u;
}
__device__ __forceinline__ float bf2f(unsigned short u) {
    return __uint_as_float(((unsigned int)u) << 16);
}
__device__ __forceinline__ float bflo(unsigned int u) { return __uint_as_float(u << 16); }
__device__ __forceinline__ float bfhi(unsigned int u) { return __uint_as_float(u & 0xFFFF0000u); }
__device__ __forceinline__ unsigned int packbf(float lo, float hi) {
    return (unsigned int)f2bf(lo) | ((unsigned int)f2bf(hi) << 16);
}
__device__ __forceinline__ float lrelu(float x) { return x > 0.0f ? x : 0.01f * x; }

// ---------------- fused prep: h->bf16, pack W1, pack W2, count dst ----------------
// Independent tasks share one dispatch; count's atomic latency hides the BW work.

__device__ __forceinline__ void pack_b_body(const float* __restrict__ Ws,
                                            const float* __restrict__ Wn,
                                            unsigned short* __restrict__ Bb,
                                            int KHALF, int KT_HALF, int idx) {
    int e  = idx & 7;
    int l  = (idx >> 3) & 63;
    int nt = (idx >> 9) & 15;
    int kt = idx >> 13;
    int n  = nt * 16 + (l & 15);
    int kh = (kt < KT_HALF ? kt : kt - KT_HALF) * 32 + (l >> 4) * 8 + e;
    const float* W = (kt < KT_HALF) ? Ws : Wn;
    float v = (kh < KHALF) ? W[(size_t)kh * OW + n] : 0.0f;
    Bb[idx] = f2bf(v);
}

__global__ void prep_kernel(const float* __restrict__ h, unsigned int* __restrict__ hb,
                            int N, int K,
                            const float* __restrict__ W1s, const float* __restrict__ W1n,
                            unsigned short* __restrict__ Bb1,
                            const float* __restrict__ W2s, const float* __restrict__ W2n,
                            unsigned short* __restrict__ Bb2,
                            const int* __restrict__ dst, int* __restrict__ cnt, int E) {
    const int tid = blockIdx.x * blockDim.x + threadIdx.x;
    const int nth = gridDim.x * blockDim.x;

    // 1) h fp32 -> bf16 padded (N * LDA1/2 uints)
    const int tot_h = N * (LDA1 / 2);
    for (int i = tid; i < tot_h; i += nth) {
        int row = i / (LDA1 / 2);
        int c   = (i - row * (LDA1 / 2)) * 2;
        float v0 = (c     < K) ? h[(size_t)row * K + c]     : 0.0f;
        float v1 = (c + 1 < K) ? h[(size_t)row * K + c + 1] : 0.0f;
        hb[i] = packbf(v0, v1);
    }
    // 2) pack W1 (KT_HALF=3)
    for (int i = tid; i < 2 * 3 * 16 * 64 * 8; i += nth)
        pack_b_body(W1s, W1n, Bb1, K, 3, i);
    // 3) pack W2 (KT_HALF=8)
    for (int i = tid; i < 2 * 8 * 16 * 64 * 8; i += nth)
        pack_b_body(W2s, W2n, Bb2, OW, 8, i);
    // 4) count dst (int4 vectorized; E % 4 handled by tail)
    const int e4 = E >> 2;
    const int4* dst4 = (const int4*)dst;
    for (int i = tid; i < e4; i += nth) {
        int4 d = dst4[i];
        atomicAdd(&cnt[d.x], 1);
        atomicAdd(&cnt[d.y], 1);
        atomicAdd(&cnt[d.z], 1);
        atomicAdd(&cnt[d.w], 1);
    }
    for (int e = e4 * 4 + tid; e < E; e += nth)
        atomicAdd(&cnt[dst[e]], 1);
}

// ---------------- CSR scan ----------------

__global__ __launch_bounds__(1024) void scan_blocksum(const int* __restrict__ cnt,
                                                      int* __restrict__ bsum, int n) {
    __shared__ int s[1024];
    int i = blockIdx.x * 1024 + threadIdx.x;
    s[threadIdx.x] = (i < n) ? cnt[i] : 0;
    __syncthreads();
    for (int off = 512; off > 0; off >>= 1) {
        if (threadIdx.x < off) s[threadIdx.x] += s[threadIdx.x + off];
        __syncthreads();
    }
    if (threadIdx.x == 0) bsum[blockIdx.x] = s[0];
}

__global__ __launch_bounds__(128) void scan_offsets(int* __restrict__ bsum, int nb) {
    __shared__ int s[128];
    int v = (threadIdx.x < nb) ? bsum[threadIdx.x] : 0;
    s[threadIdx.x] = v;
    __syncthreads();
    for (int off = 1; off < 128; off <<= 1) {
        int t = (threadIdx.x >= off) ? s[threadIdx.x - off] : 0;
        __syncthreads();
        s[threadIdx.x] += t;
        __syncthreads();
    }
    if (threadIdx.x < nb) bsum[threadIdx.x] = s[threadIdx.x] - v;   // exclusive
}

// writes rowptr AND seeds cursor with rowptr[i] (absolute cursors for fill)
__global__ __launch_bounds__(1024) void scan_write(const int* __restrict__ cnt,
                                                   const int* __restrict__ boff,
                                                   int* __restrict__ rowptr,
                                                   int* __restrict__ cursor, int n) {
    __shared__ int s[1024];
    int i = blockIdx.x * 1024 + threadIdx.x;
    int v = (i < n) ? cnt[i] : 0;
    s[threadIdx.x] = v;
    __syncthreads();
    for (int off = 1; off < 1024; off <<= 1) {
        int t = (threadIdx.x >= off) ? s[threadIdx.x - off] : 0;
        __syncthreads();
        s[threadIdx.x] += t;
        __syncthreads();
    }
    if (i < n) {
        int incl = boff[blockIdx.x] + s[threadIdx.x];
        rowptr[i + 1] = incl;
        cursor[i] = incl - v;     // exclusive == rowptr[i]
    }
    if (i == 0) rowptr[0] = 0;
}

// 4-unrolled fill: 4 independent atomics in flight per thread before dependent stores
__global__ void fill_kernel(const int* __restrict__ src, const int* __restrict__ dst,
                            int* __restrict__ cursor, int* __restrict__ csr_src, int E) {
    const int tid = blockIdx.x * blockDim.x + threadIdx.x;
    const int nth = gridDim.x * blockDim.x;
    const int e4 = E >> 2;
    const int4* dst4 = (const int4*)dst;
    const int4* src4 = (const int4*)src;
    for (int i = tid; i < e4; i += nth) {
        int4 d = dst4[i];
        int4 s = src4[i];
        int p0 = atomicAdd(&cursor[d.x], 1);
        int p1 = atomicAdd(&cursor[d.y], 1);
        int p2 = atomicAdd(&cursor[d.z], 1);
        int p3 = atomicAdd(&cursor[d.w], 1);
        csr_src[p0] = s.x;
        csr_src[p1] = s.y;
        csr_src[p2] = s.z;
        csr_src[p3] = s.w;
    }
    for (int e = e4 * 4 + tid; e < E; e += nth) {
        int pos = atomicAdd(&cursor[dst[e]], 1);
        csr_src[pos] = src[e];
    }
}

// ---------------- gathers (neighbor MEAN, atomic-free, split-half wave) ----------------

// rows of 256 bf16 (512 B); lane covers 8 cols via uint4 (16 B)
__global__ void gather_mean256(const unsigned int* __restrict__ feat,
                               const int* __restrict__ rowptr, const int* __restrict__ csr,
                               unsigned int* __restrict__ aggm, int N) {
    const int lane = threadIdx.x & (WAVE - 1);
    const int half = lane >> 5;          // 0 or 1
    const int sub  = lane & 31;          // uint4 index within row
    int wave = (blockIdx.x * blockDim.x + threadIdx.x) / WAVE;
    int nw   = (gridDim.x * blockDim.x) / WAVE;

    for (int v = wave; v < N; v += nw) {
        const int beg = rowptr[v], deg = rowptr[v + 1] - beg;
        const int npairs = deg >> 1;
        float l0 = 0.f, h0 = 0.f, l1 = 0.f, h1 = 0.f,
              l2 = 0.f, h2 = 0.f, l3 = 0.f, h3 = 0.f;

        int p = 0;
        for (; p + 3 < npairs; p += 4) {
            int i0 = csr[beg + 2 * (p + 0) + half];
            int i1 = csr[beg + 2 * (p + 1) + half];
            int i2 = csr[beg + 2 * (p + 2) + half];
            int i3 = csr[beg + 2 * (p + 3) + half];
            uint4 x0 = *(const uint4*)(feat + (size_t)i0 * 128 + sub * 4);
            uint4 x1 = *(const uint4*)(feat + (size_t)i1 * 128 + sub * 4);
            uint4 x2 = *(const uint4*)(feat + (size_t)i2 * 128 + sub * 4);
            uint4 x3 = *(const uint4*)(feat + (size_t)i3 * 128 + sub * 4);
            l0 += bflo(x0.x) + bflo(x1.x) + bflo(x2.x) + bflo(x3.x);
            h0 += bfhi(x0.x) + bfhi(x1.x) + bfhi(x2.x) + bfhi(x3.x);
            l1 += bflo(x0.y) + bflo(x1.y) + bflo(x2.y) + bflo(x3.y);
            h1 += bfhi(x0.y) + bfhi(x1.y) + bfhi(x2.y) + bfhi(x3.y);
            l2 += bflo(x0.z) + bflo(x1.z) + bflo(x2.z) + bflo(x3.z);
            h2 += bfhi(x0.z) + bfhi(x1.z) + bfhi(x2.z) + bfhi(x3.z);
            l3 += bflo(x0.w) + bflo(x1.w) + bflo(x2.w) + bflo(x3.w);
            h3 += bfhi(x0.w) + bfhi(x1.w) + bfhi(x2.w) + bfhi(x3.w);
        }
        for (; p < npairs; ++p) {
            int i0 = csr[beg + 2 * p + half];
            uint4 x0 = *(const uint4*)(feat + (size_t)i0 * 128 + sub * 4);
            l0 += bflo(x0.x); h0 += bfhi(x0.x);
            l1 += bflo(x0.y); h1 += bfhi(x0.y);
            l2 += bflo(x0.z); h2 += bfhi(x0.z);
            l3 += bflo(x0.w); h3 += bfhi(x0.w);
        }
        if ((deg & 1) && half == 0) {     // tail edge handled by low half
            int i0 = csr[beg + deg - 1];
            uint4 x0 = *(const uint4*)(feat + (size_t)i0 * 128 + sub * 4);
            l0 += bflo(x0.x); h0 += bfhi(x0.x);
            l1 += bflo(x0.y); h1 += bfhi(x0.y);
            l2 += bflo(x0.z); h2 += bfhi(x0.z);
            l3 += bflo(x0.w); h3 += bfhi(x0.w);
        }
        // combine halves
        l0 += __shfl_xor(l0, 32); h0 += __shfl_xor(h0, 32);
        l1 += __shfl_xor(l1, 32); h1 += __shfl_xor(h1, 32);
        l2 += __shfl_xor(l2, 32); h2 += __shfl_xor(h2, 32);
        l3 += __shfl_xor(l3, 32); h3 += __shfl_xor(h3, 32);

        if (half == 0) {
            float inv = 1.0f / fmaxf((float)deg, 1.0f);
            uint4 o;
            o.x = packbf(l0 * inv, h0 * inv);
            o.y = packbf(l1 * inv, h1 * inv);
            o.z = packbf(l2 * inv, h2 * inv);
            o.w = packbf(l3 * inv, h3 * inv);
            *(uint4*)(aggm + (size_t)v * 128 + sub * 4) = o;
        }
    }
}

// rows of 96 bf16 (192 B = 48 uints); 24 active lanes/half, uint2 (8 B) each
__global__ void gather_mean_pad(const unsigned int* __restrict__ feat,
                                const int* __restrict__ rowptr, const int* __restrict__ csr,
                                unsigned int* __restrict__ aggm, int N) {
    const int lane = threadIdx.x & (WAVE - 1);
    const int half = lane >> 5;
    const int sub  = lane & 31;
    const bool act = sub < 24;
    int wave = (blockIdx.x * blockDim.x + threadIdx.x) / WAVE;
    int nw   = (gridDim.x * blockDim.x) / WAVE;

    for (int v = wave; v < N; v += nw) {
        const int beg = rowptr[v], deg = rowptr[v + 1] - beg;
        const int npairs = deg >> 1;
        float l0 = 0.f, h0 = 0.f, l1 = 0.f, h1 = 0.f;

        int p = 0;
        for (; p + 3 < npairs; p += 4) {
            int i0 = csr[beg + 2 * (p + 0) + half];
            int i1 = csr[beg + 2 * (p + 1) + half];
            int i2 = csr[beg + 2 * (p + 2) + half];
            int i3 = csr[beg + 2 * (p + 3) + half];
            if (act) {
                uint2 x0 = *(const uint2*)(feat + (size_t)i0 * 48 + sub * 2);
                uint2 x1 = *(const uint2*)(feat + (size_t)i1 * 48 + sub * 2);
                uint2 x2 = *(const uint2*)(feat + (size_t)i2 * 48 + sub * 2);
                uint2 x3 = *(const uint2*)(feat + (size_t)i3 * 48 + sub * 2);
                l0 += bflo(x0.x) + bflo(x1.x) + bflo(x2.x) + bflo(x3.x);
                h0 += bfhi(x0.x) + bfhi(x1.x) + bfhi(x2.x) + bfhi(x3.x);
                l1 += bflo(x0.y) + bflo(x1.y) + bflo(x2.y) + bflo(x3.y);
                h1 += bfhi(x0.y) + bfhi(x1.y) + bfhi(x2.y) + bfhi(x3.y);
            }
        }
        for (; p < npairs; ++p) {
            int i0 = csr[beg + 2 * p + half];
            if (act) {
                uint2 x0 = *(const uint2*)(feat + (size_t)i0 * 48 + sub * 2);
                l0 += bflo(x0.x); h0 += bfhi(x0.x);
                l1 += bflo(x0.y); h1 += bfhi(x0.y);
            }
        }
        if ((deg & 1) && half == 0) {
            int i0 = csr[beg + deg - 1];
            if (act) {
                uint2 x0 = *(const uint2*)(feat + (size_t)i0 * 48 + sub * 2);
                l0 += bflo(x0.x); h0 += bfhi(x0.x);
                l1 += bflo(x0.y); h1 += bfhi(x0.y);
            }
        }
        l0 += __shfl_xor(l0, 32); h0 += __shfl_xor(h0, 32);
        l1 += __shfl_xor(l1, 32); h1 += __shfl_xor(h1, 32);

        if (half == 0 && act) {
            float inv = 1.0f / fmaxf((float)deg, 1.0f);
            uint2 o;
            o.x = packbf(l0 * inv, h0 * inv);
            o.y = packbf(l1 * inv, h1 * inv);
            *(uint2*)(aggm + (size_t)v * 48 + sub * 2) = o;
        }
    }
}

// ---------------- MFMA SAGE GEMM (LDS-free, barrier-free, bf16 A) ----------------
template<int KT_HALF>
__global__ __launch_bounds__(512) void sage_mfma(
    const unsigned short* __restrict__ Hs, const unsigned short* __restrict__ Hn, int lda,
    const unsigned short* __restrict__ Bb, const float* __restrict__ bias,
    unsigned short* __restrict__ outb, int M)
{
    const int t    = threadIdx.x;
    const int lane = t & 63, wid = t >> 6;
    const int wm   = wid >> 1, wn = wid & 1;
    const int brow = blockIdx.x * 128;
    const int lrow = lane & 15, kblk = lane >> 4;

    const int r0 = brow + wm * 32 + lrow;
    const int r1 = r0 + 16;
    const int r0c = (r0 < M) ? r0 : (M - 1);
    const int r1c = (r1 < M) ? r1 : (M - 1);

    f32x4 acc[2][8];
#pragma unroll
    for (int rt = 0; rt < 2; ++rt)
#pragma unroll
        for (int ct = 0; ct < 8; ++ct) acc[rt][ct] = (f32x4)0.0f;

    const int NT = 2 * KT_HALF;
#pragma unroll 4
    for (int kt = 0; kt < NT; ++kt) {
        const bool self = kt < KT_HALF;
        const int  kh   = (self ? kt : kt - KT_HALF) * 32 + kblk * 8;
        const unsigned short* src = self ? Hs : Hn;
        bf16x8 a0 = *(const bf16x8*)(src + (size_t)r0c * lda + kh);
        bf16x8 a1 = *(const bf16x8*)(src + (size_t)r1c * lda + kh);
        const unsigned short* bp = Bb + (((size_t)kt * 16 + wn * 8) * 64 + lane) * 8;
#pragma unroll
        for (int ct = 0; ct < 8; ++ct) {
            bf16x8 b = *(const bf16x8*)(bp + (size_t)ct * 64 * 8);
            acc[0][ct] = __builtin_amdgcn_mfma_f32_16x16x32_bf16(a0, b, acc[0][ct], 0, 0, 0);
            acc[1][ct] = __builtin_amdgcn_mfma_f32_16x16x32_bf16(a1, b, acc[1][ct], 0, 0, 0);
        }
    }

    // D layout: col=lane&15, row=(lane>>4)*4+j
#pragma unroll
    for (int rt = 0; rt < 2; ++rt) {
        int rbase = brow + wm * 32 + rt * 16 + kblk * 4;
#pragma unroll
        for (int ct = 0; ct < 8; ++ct) {
            int col = wn * 128 + ct * 16 + lrow;
            float vb = bias[col];
#pragma unroll
            for (int j = 0; j < 4; ++j) {
                int row = rbase + j;
                if (row < M)
                    outb[(size_t)row * OW + col] = f2bf(lrelu(acc[rt][ct][j] + vb));
            }
        }
    }
}

// ---------------- per-graph mean pool + FC (graph_ids sorted) ----------------

__global__ __launch_bounds__(256) void pool_fc_kernel(
    const unsigned short* __restrict__ x, const int* __restrict__ gid,
    const float* __restrict__ Wfc, const float* __restrict__ bfc,
    float* __restrict__ out, int N, int C)
{
    int g = blockIdx.x;
    int lo = 0, hi = N;
    while (lo < hi) { int m = (lo + hi) >> 1; if (gid[m] < g) lo = m + 1; else hi = m; }
    int beg = lo;
    hi = N;
    while (lo < hi) { int m = (lo + hi) >> 1; if (gid[m] <= g) lo = m + 1; else hi = m; }
    int end = lo;

    __shared__ float hg[OW];
    int c = threadIdx.x;
    float s0 = 0.f, s1 = 0.f, s2 = 0.f, s3 = 0.f;
    int r = beg;
    for (; r + 3 < end; r += 4) {
        s0 += bf2f(x[(size_t)(r + 0) * OW + c]);
        s1 += bf2f(x[(size_t)(r + 1) * OW + c]);
        s2 += bf2f(x[(size_t)(r + 2) * OW + c]);
        s3 += bf2f(x[(size_t)(r + 3) * OW + c]);
    }
    for (; r < end; ++r) s0 += bf2f(x[(size_t)r * OW + c]);
    float s = (s0 + s1) + (s2 + s3);
    float inv = (end > beg) ? 1.0f / (float)(end - beg) : 0.0f;
    hg[c] = s * inv;
    __syncthreads();

    if (c < C) {
        float a = bfc[c];
        for (int k = 0; k < OW; ++k)
            a = fmaf(hg[k], Wfc[(size_t)k * C + c], a);
        out[(size_t)g * C + c] = a;
    }
}

extern "C" void kernel_launch(void* const* d_in, const int* in_sizes, int n_in,
                              void* d_out, int out_size, void* d_ws, size_t ws_size,
                              hipStream_t stream) {
    const float* h   = (const float*)d_in[0];
    const float* W1s = (const float*)d_in[1];
    const float* W1n = (const float*)d_in[2];
    const float* b1  = (const float*)d_in[3];
    const float* W2s = (const float*)d_in[4];
    const float* W2n = (const float*)d_in[5];
    const float* b2  = (const float*)d_in[6];
    const float* Wfc = (const float*)d_in[7];
    const float* bfc = (const float*)d_in[8];
    const int*   src = (const int*)d_in[9];
    const int*   dst = (const int*)d_in[10];
    const int*   gid = (const int*)d_in[11];

    const int N  = in_sizes[11];          // 100000
    const int E  = in_sizes[9];           // 1600000
    const int K1 = in_sizes[0] / N;       // 67
    const int NC = in_sizes[8];           // 18
    const int G  = out_size / NC;         // 256

    char* w = (char*)d_ws;
    auto alloc = [&](size_t bytes) { char* p = w; w += (bytes + 255) & ~(size_t)255; return p; };
    unsigned int*   hb     = (unsigned int*)alloc((size_t)N * (LDA1 / 2) * 4);
    unsigned int*   agg1b  = (unsigned int*)alloc((size_t)N * (LDA1 / 2) * 4);
    unsigned short* x1b    = (unsigned short*)alloc((size_t)N * OW * 2);
    unsigned short* agg2b  = (unsigned short*)alloc((size_t)N * OW * 2);
    int*            rowptr = (int*)alloc((size_t)(N + 1) * 4);
    int*            cursor = (int*)alloc((size_t)N * 4);
    int*            csr    = (int*)alloc((size_t)E * 4);
    int*            bsum   = (int*)alloc(1024 * 4);
    unsigned short* Bb1    = (unsigned short*)alloc((size_t)2 * 3 * 16 * 64 * 8 * 2);
    unsigned short* Bb2    = (unsigned short*)alloc((size_t)2 * 8 * 16 * 64 * 8 * 2);

    float* out = (float*)d_out;
    const int nb = (N + 1023) / 1024;

    // fused prep: h->bf16, pack W1/W2, count dst (into cursor)
    hipMemsetAsync(cursor, 0, (size_t)N * sizeof(int), stream);
    prep_kernel<<<2048, 256, 0, stream>>>(h, hb, N, K1, W1s, W1n, Bb1, W2s, W2n, Bb2,
                                          dst, cursor, E);

    // CSR scan (cursor seeded with rowptr for absolute fill)
    scan_blocksum<<<nb, 1024, 0, stream>>>(cursor, bsum, N);
    scan_offsets<<<1, 128, 0, stream>>>(bsum, nb);
    scan_write<<<nb, 1024, 0, stream>>>(cursor, bsum, rowptr, cursor, N);
    fill_kernel<<<2048, 256, 0, stream>>>(src, dst, cursor, csr, E);

    const int gemm_grid = (N + 127) / 128;

    // layer 1
    gather_mean_pad<<<4096, 256, 0, stream>>>(hb, rowptr, csr, agg1b, N);
    sage_mfma<3><<<gemm_grid, 512, 0, stream>>>((const unsigned short*)hb,
                                                (const unsigned short*)agg1b, LDA1,
                                                Bb1, b1, x1b, N);

    // layer 2 (in place over x1b)
    gather_mean256<<<4096, 256, 0, stream>>>((const unsigned int*)x1b, rowptr, csr,
                                             (unsigned int*)agg2b, N);
    sage_mfma<8><<<gemm_grid, 512, 0, stream>>>(x1b, agg2b, OW, Bb2, b2, x1b, N);

    // per-graph mean pool + classifier
    pool_fc_kernel<<<G, 256, 0, stream>>>(x1b, gid, Wfc, bfc, out, N, NC);
}

// Round 8
// 460.167 us; speedup vs baseline: 1.2211x; 1.2211x over previous
//
#include <hip/hip_runtime.h>

#define WAVE 64
#define OW 256    // hidden width
#define LDA1 96   // padded layer-1 K (67 -> 96, zero pad)

typedef short bf16x8 __attribute__((ext_vector_type(8)));
typedef float f32x4  __attribute__((ext_vector_type(4)));

__device__ __forceinline__ unsigned short f2bf(float f) {   // RNE fp32 -> bf16
    unsigned int u = __float_as_uint(f);
    u = (u + 0x7FFF + ((u >> 16) & 1)) >> 16;
    return (unsigned short)u;
}
__device__ __forceinline__ float bf2f(unsigned short u) {
    return __uint_as_float(((unsigned int)u) << 16);
}
__device__ __forceinline__ float bflo(unsigned int u) { return __uint_as_float(u << 16); }
__device__ __forceinline__ float bfhi(unsigned int u) { return __uint_as_float(u & 0xFFFF0000u); }
__device__ __forceinline__ unsigned int packbf(float lo, float hi) {
    return (unsigned int)f2bf(lo) | ((unsigned int)f2bf(hi) << 16);
}
__device__ __forceinline__ float lrelu(float x) { return x > 0.0f ? x : 0.01f * x; }

// ---------------- fused prep: h->bf16, pack W1, pack W2, count dst (+rank) ----------------
// The count atomic RETURNS each edge's rank within its dst bucket -> fill needs no atomics.

__device__ __forceinline__ void pack_b_body(const float* __restrict__ Ws,
                                            const float* __restrict__ Wn,
                                            unsigned short* __restrict__ Bb,
                                            int KHALF, int KT_HALF, int idx) {
    int e  = idx & 7;
    int l  = (idx >> 3) & 63;
    int nt = (idx >> 9) & 15;
    int kt = idx >> 13;
    int n  = nt * 16 + (l & 15);
    int kh = (kt < KT_HALF ? kt : kt - KT_HALF) * 32 + (l >> 4) * 8 + e;
    const float* W = (kt < KT_HALF) ? Ws : Wn;
    float v = (kh < KHALF) ? W[(size_t)kh * OW + n] : 0.0f;
    Bb[idx] = f2bf(v);
}

__global__ void prep_kernel(const float* __restrict__ h, unsigned int* __restrict__ hb,
                            int N, int K,
                            const float* __restrict__ W1s, const float* __restrict__ W1n,
                            unsigned short* __restrict__ Bb1,
                            const float* __restrict__ W2s, const float* __restrict__ W2n,
                            unsigned short* __restrict__ Bb2,
                            const int* __restrict__ dst, int* __restrict__ cnt,
                            int* __restrict__ rank, int E) {
    const int tid = blockIdx.x * blockDim.x + threadIdx.x;
    const int nth = gridDim.x * blockDim.x;

    // 1) h fp32 -> bf16 padded (N * LDA1/2 uints)
    const int tot_h = N * (LDA1 / 2);
    for (int i = tid; i < tot_h; i += nth) {
        int row = i / (LDA1 / 2);
        int c   = (i - row * (LDA1 / 2)) * 2;
        float v0 = (c     < K) ? h[(size_t)row * K + c]     : 0.0f;
        float v1 = (c + 1 < K) ? h[(size_t)row * K + c + 1] : 0.0f;
        hb[i] = packbf(v0, v1);
    }
    // 2) pack W1 (KT_HALF=3)
    for (int i = tid; i < 2 * 3 * 16 * 64 * 8; i += nth)
        pack_b_body(W1s, W1n, Bb1, K, 3, i);
    // 3) pack W2 (KT_HALF=8)
    for (int i = tid; i < 2 * 8 * 16 * 64 * 8; i += nth)
        pack_b_body(W2s, W2n, Bb2, OW, 8, i);
    // 4) count dst, capturing per-edge rank
    const int e4 = E >> 2;
    const int4* dst4 = (const int4*)dst;
    int4* rank4 = (int4*)rank;
    for (int i = tid; i < e4; i += nth) {
        int4 d = dst4[i];
        int4 r;
        r.x = atomicAdd(&cnt[d.x], 1);
        r.y = atomicAdd(&cnt[d.y], 1);
        r.z = atomicAdd(&cnt[d.z], 1);
        r.w = atomicAdd(&cnt[d.w], 1);
        rank4[i] = r;
    }
    for (int e = e4 * 4 + tid; e < E; e += nth)
        rank[e] = atomicAdd(&cnt[dst[e]], 1);
}

// ---------------- CSR scan ----------------

__global__ __launch_bounds__(1024) void scan_blocksum(const int* __restrict__ cnt,
                                                      int* __restrict__ bsum, int n) {
    __shared__ int s[1024];
    int i = blockIdx.x * 1024 + threadIdx.x;
    s[threadIdx.x] = (i < n) ? cnt[i] : 0;
    __syncthreads();
    for (int off = 512; off > 0; off >>= 1) {
        if (threadIdx.x < off) s[threadIdx.x] += s[threadIdx.x + off];
        __syncthreads();
    }
    if (threadIdx.x == 0) bsum[blockIdx.x] = s[0];
}

__global__ __launch_bounds__(128) void scan_offsets(int* __restrict__ bsum, int nb) {
    __shared__ int s[128];
    int v = (threadIdx.x < nb) ? bsum[threadIdx.x] : 0;
    s[threadIdx.x] = v;
    __syncthreads();
    for (int off = 1; off < 128; off <<= 1) {
        int t = (threadIdx.x >= off) ? s[threadIdx.x - off] : 0;
        __syncthreads();
        s[threadIdx.x] += t;
        __syncthreads();
    }
    if (threadIdx.x < nb) bsum[threadIdx.x] = s[threadIdx.x] - v;   // exclusive
}

__global__ __launch_bounds__(1024) void scan_write(const int* __restrict__ cnt,
                                                   const int* __restrict__ boff,
                                                   int* __restrict__ rowptr, int n) {
    __shared__ int s[1024];
    int i = blockIdx.x * 1024 + threadIdx.x;
    int v = (i < n) ? cnt[i] : 0;
    s[threadIdx.x] = v;
    __syncthreads();
    for (int off = 1; off < 1024; off <<= 1) {
        int t = (threadIdx.x >= off) ? s[threadIdx.x - off] : 0;
        __syncthreads();
        s[threadIdx.x] += t;
        __syncthreads();
    }
    if (i < n) rowptr[i + 1] = boff[blockIdx.x] + s[threadIdx.x];
    if (i == 0) rowptr[0] = 0;
}

// atomic-free fill: pos = rowptr[dst] + rank
__global__ void fill_kernel(const int* __restrict__ src, const int* __restrict__ dst,
                            const int* __restrict__ rank, const int* __restrict__ rowptr,
                            int* __restrict__ csr_src, int E) {
    const int tid = blockIdx.x * blockDim.x + threadIdx.x;
    const int nth = gridDim.x * blockDim.x;
    const int e4 = E >> 2;
    const int4* dst4 = (const int4*)dst;
    const int4* src4 = (const int4*)src;
    const int4* rank4 = (const int4*)rank;
    for (int i = tid; i < e4; i += nth) {
        int4 d = dst4[i];
        int4 s = src4[i];
        int4 r = rank4[i];
        csr_src[rowptr[d.x] + r.x] = s.x;
        csr_src[rowptr[d.y] + r.y] = s.y;
        csr_src[rowptr[d.z] + r.z] = s.z;
        csr_src[rowptr[d.w] + r.w] = s.w;
    }
    for (int e = e4 * 4 + tid; e < E; e += nth)
        csr_src[rowptr[dst[e]] + rank[e]] = src[e];
}

// ---------------- gathers (neighbor MEAN, atomic-free, split-half wave) ----------------

// rows of 256 bf16 (512 B); lane covers 8 cols via uint4 (16 B)
__global__ void gather_mean256(const unsigned int* __restrict__ feat,
                               const int* __restrict__ rowptr, const int* __restrict__ csr,
                               unsigned int* __restrict__ aggm, int N) {
    const int lane = threadIdx.x & (WAVE - 1);
    const int half = lane >> 5;          // 0 or 1
    const int sub  = lane & 31;          // uint4 index within row
    int wave = (blockIdx.x * blockDim.x + threadIdx.x) / WAVE;
    int nw   = (gridDim.x * blockDim.x) / WAVE;

    for (int v = wave; v < N; v += nw) {
        const int beg = rowptr[v], deg = rowptr[v + 1] - beg;
        const int npairs = deg >> 1;
        float l0 = 0.f, h0 = 0.f, l1 = 0.f, h1 = 0.f,
              l2 = 0.f, h2 = 0.f, l3 = 0.f, h3 = 0.f;

        int p = 0;
        for (; p + 3 < npairs; p += 4) {
            int i0 = csr[beg + 2 * (p + 0) + half];
            int i1 = csr[beg + 2 * (p + 1) + half];
            int i2 = csr[beg + 2 * (p + 2) + half];
            int i3 = csr[beg + 2 * (p + 3) + half];
            uint4 x0 = *(const uint4*)(feat + (size_t)i0 * 128 + sub * 4);
            uint4 x1 = *(const uint4*)(feat + (size_t)i1 * 128 + sub * 4);
            uint4 x2 = *(const uint4*)(feat + (size_t)i2 * 128 + sub * 4);
            uint4 x3 = *(const uint4*)(feat + (size_t)i3 * 128 + sub * 4);
            l0 += bflo(x0.x) + bflo(x1.x) + bflo(x2.x) + bflo(x3.x);
            h0 += bfhi(x0.x) + bfhi(x1.x) + bfhi(x2.x) + bfhi(x3.x);
            l1 += bflo(x0.y) + bflo(x1.y) + bflo(x2.y) + bflo(x3.y);
            h1 += bfhi(x0.y) + bfhi(x1.y) + bfhi(x2.y) + bfhi(x3.y);
            l2 += bflo(x0.z) + bflo(x1.z) + bflo(x2.z) + bflo(x3.z);
            h2 += bfhi(x0.z) + bfhi(x1.z) + bfhi(x2.z) + bfhi(x3.z);
            l3 += bflo(x0.w) + bflo(x1.w) + bflo(x2.w) + bflo(x3.w);
            h3 += bfhi(x0.w) + bfhi(x1.w) + bfhi(x2.w) + bfhi(x3.w);
        }
        for (; p < npairs; ++p) {
            int i0 = csr[beg + 2 * p + half];
            uint4 x0 = *(const uint4*)(feat + (size_t)i0 * 128 + sub * 4);
            l0 += bflo(x0.x); h0 += bfhi(x0.x);
            l1 += bflo(x0.y); h1 += bfhi(x0.y);
            l2 += bflo(x0.z); h2 += bfhi(x0.z);
            l3 += bflo(x0.w); h3 += bfhi(x0.w);
        }
        if ((deg & 1) && half == 0) {     // tail edge handled by low half
            int i0 = csr[beg + deg - 1];
            uint4 x0 = *(const uint4*)(feat + (size_t)i0 * 128 + sub * 4);
            l0 += bflo(x0.x); h0 += bfhi(x0.x);
            l1 += bflo(x0.y); h1 += bfhi(x0.y);
            l2 += bflo(x0.z); h2 += bfhi(x0.z);
            l3 += bflo(x0.w); h3 += bfhi(x0.w);
        }
        // combine halves
        l0 += __shfl_xor(l0, 32); h0 += __shfl_xor(h0, 32);
        l1 += __shfl_xor(l1, 32); h1 += __shfl_xor(h1, 32);
        l2 += __shfl_xor(l2, 32); h2 += __shfl_xor(h2, 32);
        l3 += __shfl_xor(l3, 32); h3 += __shfl_xor(h3, 32);

        if (half == 0) {
            float inv = 1.0f / fmaxf((float)deg, 1.0f);
            uint4 o;
            o.x = packbf(l0 * inv, h0 * inv);
            o.y = packbf(l1 * inv, h1 * inv);
            o.z = packbf(l2 * inv, h2 * inv);
            o.w = packbf(l3 * inv, h3 * inv);
            *(uint4*)(aggm + (size_t)v * 128 + sub * 4) = o;
        }
    }
}

// rows of 96 bf16 (192 B = 48 uints); 24 active lanes/half, uint2 (8 B) each
__global__ void gather_mean_pad(const unsigned int* __restrict__ feat,
                                const int* __restrict__ rowptr, const int* __restrict__ csr,
                                unsigned int* __restrict__ aggm, int N) {
    const int lane = threadIdx.x & (WAVE - 1);
    const int half = lane >> 5;
    const int sub  = lane & 31;
    const bool act = sub < 24;
    int wave = (blockIdx.x * blockDim.x + threadIdx.x) / WAVE;
    int nw   = (gridDim.x * blockDim.x) / WAVE;

    for (int v = wave; v < N; v += nw) {
        const int beg = rowptr[v], deg = rowptr[v + 1] - beg;
        const int npairs = deg >> 1;
        float l0 = 0.f, h0 = 0.f, l1 = 0.f, h1 = 0.f;

        int p = 0;
        for (; p + 3 < npairs; p += 4) {
            int i0 = csr[beg + 2 * (p + 0) + half];
            int i1 = csr[beg + 2 * (p + 1) + half];
            int i2 = csr[beg + 2 * (p + 2) + half];
            int i3 = csr[beg + 2 * (p + 3) + half];
            if (act) {
                uint2 x0 = *(const uint2*)(feat + (size_t)i0 * 48 + sub * 2);
                uint2 x1 = *(const uint2*)(feat + (size_t)i1 * 48 + sub * 2);
                uint2 x2 = *(const uint2*)(feat + (size_t)i2 * 48 + sub * 2);
                uint2 x3 = *(const uint2*)(feat + (size_t)i3 * 48 + sub * 2);
                l0 += bflo(x0.x) + bflo(x1.x) + bflo(x2.x) + bflo(x3.x);
                h0 += bfhi(x0.x) + bfhi(x1.x) + bfhi(x2.x) + bfhi(x3.x);
                l1 += bflo(x0.y) + bflo(x1.y) + bflo(x2.y) + bflo(x3.y);
                h1 += bfhi(x0.y) + bfhi(x1.y) + bfhi(x2.y) + bfhi(x3.y);
            }
        }
        for (; p < npairs; ++p) {
            int i0 = csr[beg + 2 * p + half];
            if (act) {
                uint2 x0 = *(const uint2*)(feat + (size_t)i0 * 48 + sub * 2);
                l0 += bflo(x0.x); h0 += bfhi(x0.x);
                l1 += bflo(x0.y); h1 += bfhi(x0.y);
            }
        }
        if ((deg & 1) && half == 0) {
            int i0 = csr[beg + deg - 1];
            if (act) {
                uint2 x0 = *(const uint2*)(feat + (size_t)i0 * 48 + sub * 2);
                l0 += bflo(x0.x); h0 += bfhi(x0.x);
                l1 += bflo(x0.y); h1 += bfhi(x0.y);
            }
        }
        l0 += __shfl_xor(l0, 32); h0 += __shfl_xor(h0, 32);
        l1 += __shfl_xor(l1, 32); h1 += __shfl_xor(h1, 32);

        if (half == 0 && act) {
            float inv = 1.0f / fmaxf((float)deg, 1.0f);
            uint2 o;
            o.x = packbf(l0 * inv, h0 * inv);
            o.y = packbf(l1 * inv, h1 * inv);
            *(uint2*)(aggm + (size_t)v * 48 + sub * 2) = o;
        }
    }
}

// ---------------- MFMA SAGE GEMM (LDS-free, barrier-free, bf16 A) ----------------
template<int KT_HALF>
__global__ __launch_bounds__(512) void sage_mfma(
    const unsigned short* __restrict__ Hs, const unsigned short* __restrict__ Hn, int lda,
    const unsigned short* __restrict__ Bb, const float* __restrict__ bias,
    unsigned short* __restrict__ outb, int M)
{
    const int t    = threadIdx.x;
    const int lane = t & 63, wid = t >> 6;
    const int wm   = wid >> 1, wn = wid & 1;
    const int brow = blockIdx.x * 128;
    const int lrow = lane & 15, kblk = lane >> 4;

    const int r0 = brow + wm * 32 + lrow;
    const int r1 = r0 + 16;
    const int r0c = (r0 < M) ? r0 : (M - 1);
    const int r1c = (r1 < M) ? r1 : (M - 1);

    f32x4 acc[2][8];
#pragma unroll
    for (int rt = 0; rt < 2; ++rt)
#pragma unroll
        for (int ct = 0; ct < 8; ++ct) acc[rt][ct] = (f32x4)0.0f;

    const int NT = 2 * KT_HALF;
#pragma unroll 4
    for (int kt = 0; kt < NT; ++kt) {
        const bool self = kt < KT_HALF;
        const int  kh   = (self ? kt : kt - KT_HALF) * 32 + kblk * 8;
        const unsigned short* src = self ? Hs : Hn;
        bf16x8 a0 = *(const bf16x8*)(src + (size_t)r0c * lda + kh);
        bf16x8 a1 = *(const bf16x8*)(src + (size_t)r1c * lda + kh);
        const unsigned short* bp = Bb + (((size_t)kt * 16 + wn * 8) * 64 + lane) * 8;
#pragma unroll
        for (int ct = 0; ct < 8; ++ct) {
            bf16x8 b = *(const bf16x8*)(bp + (size_t)ct * 64 * 8);
            acc[0][ct] = __builtin_amdgcn_mfma_f32_16x16x32_bf16(a0, b, acc[0][ct], 0, 0, 0);
            acc[1][ct] = __builtin_amdgcn_mfma_f32_16x16x32_bf16(a1, b, acc[1][ct], 0, 0, 0);
        }
    }

    // D layout: col=lane&15, row=(lane>>4)*4+j
#pragma unroll
    for (int rt = 0; rt < 2; ++rt) {
        int rbase = brow + wm * 32 + rt * 16 + kblk * 4;
#pragma unroll
        for (int ct = 0; ct < 8; ++ct) {
            int col = wn * 128 + ct * 16 + lrow;
            float vb = bias[col];
#pragma unroll
            for (int j = 0; j < 4; ++j) {
                int row = rbase + j;
                if (row < M)
                    outb[(size_t)row * OW + col] = f2bf(lrelu(acc[rt][ct][j] + vb));
            }
        }
    }
}

// ---------------- per-graph mean pool + FC (graph_ids sorted) ----------------

__global__ __launch_bounds__(256) void pool_fc_kernel(
    const unsigned short* __restrict__ x, const int* __restrict__ gid,
    const float* __restrict__ Wfc, const float* __restrict__ bfc,
    float* __restrict__ out, int N, int C)
{
    int g = blockIdx.x;
    int lo = 0, hi = N;
    while (lo < hi) { int m = (lo + hi) >> 1; if (gid[m] < g) lo = m + 1; else hi = m; }
    int beg = lo;
    hi = N;
    while (lo < hi) { int m = (lo + hi) >> 1; if (gid[m] <= g) lo = m + 1; else hi = m; }
    int end = lo;

    __shared__ float hg[OW];
    int c = threadIdx.x;
    float s0 = 0.f, s1 = 0.f, s2 = 0.f, s3 = 0.f;
    int r = beg;
    for (; r + 3 < end; r += 4) {
        s0 += bf2f(x[(size_t)(r + 0) * OW + c]);
        s1 += bf2f(x[(size_t)(r + 1) * OW + c]);
        s2 += bf2f(x[(size_t)(r + 2) * OW + c]);
        s3 += bf2f(x[(size_t)(r + 3) * OW + c]);
    }
    for (; r < end; ++r) s0 += bf2f(x[(size_t)r * OW + c]);
    float s = (s0 + s1) + (s2 + s3);
    float inv = (end > beg) ? 1.0f / (float)(end - beg) : 0.0f;
    hg[c] = s * inv;
    __syncthreads();

    if (c < C) {
        float a = bfc[c];
        for (int k = 0; k < OW; ++k)
            a = fmaf(hg[k], Wfc[(size_t)k * C + c], a);
        out[(size_t)g * C + c] = a;
    }
}

extern "C" void kernel_launch(void* const* d_in, const int* in_sizes, int n_in,
                              void* d_out, int out_size, void* d_ws, size_t ws_size,
                              hipStream_t stream) {
    const float* h   = (const float*)d_in[0];
    const float* W1s = (const float*)d_in[1];
    const float* W1n = (const float*)d_in[2];
    const float* b1  = (const float*)d_in[3];
    const float* W2s = (const float*)d_in[4];
    const float* W2n = (const float*)d_in[5];
    const float* b2  = (const float*)d_in[6];
    const float* Wfc = (const float*)d_in[7];
    const float* bfc = (const float*)d_in[8];
    const int*   src = (const int*)d_in[9];
    const int*   dst = (const int*)d_in[10];
    const int*   gid = (const int*)d_in[11];

    const int N  = in_sizes[11];          // 100000
    const int E  = in_sizes[9];           // 1600000
    const int K1 = in_sizes[0] / N;       // 67
    const int NC = in_sizes[8];           // 18
    const int G  = out_size / NC;         // 256

    char* w = (char*)d_ws;
    auto alloc = [&](size_t bytes) { char* p = w; w += (bytes + 255) & ~(size_t)255; return p; };
    unsigned int*   hb     = (unsigned int*)alloc((size_t)N * (LDA1 / 2) * 4);
    unsigned int*   agg1b  = (unsigned int*)alloc((size_t)N * (LDA1 / 2) * 4);
    unsigned short* x1b    = (unsigned short*)alloc((size_t)N * OW * 2);
    unsigned short* agg2b  = (unsigned short*)alloc((size_t)N * OW * 2);
    int*            rowptr = (int*)alloc((size_t)(N + 1) * 4);
    int*            cnt    = (int*)alloc((size_t)N * 4);
    int*            csr    = (int*)alloc((size_t)E * 4);
    int*            rank   = (int*)alloc((size_t)E * 4);
    int*            bsum   = (int*)alloc(1024 * 4);
    unsigned short* Bb1    = (unsigned short*)alloc((size_t)2 * 3 * 16 * 64 * 8 * 2);
    unsigned short* Bb2    = (unsigned short*)alloc((size_t)2 * 8 * 16 * 64 * 8 * 2);

    float* out = (float*)d_out;
    const int nb = (N + 1023) / 1024;

    // fused prep: h->bf16, pack W1/W2, count dst + per-edge rank
    hipMemsetAsync(cnt, 0, (size_t)N * sizeof(int), stream);
    prep_kernel<<<2048, 256, 0, stream>>>(h, hb, N, K1, W1s, W1n, Bb1, W2s, W2n, Bb2,
                                          dst, cnt, rank, E);

    // CSR scan + atomic-free fill
    scan_blocksum<<<nb, 1024, 0, stream>>>(cnt, bsum, N);
    scan_offsets<<<1, 128, 0, stream>>>(bsum, nb);
    scan_write<<<nb, 1024, 0, stream>>>(cnt, bsum, rowptr, N);
    fill_kernel<<<2048, 256, 0, stream>>>(src, dst, rank, rowptr, csr, E);

    const int gemm_grid = (N + 127) / 128;

    // layer 1
    gather_mean_pad<<<4096, 256, 0, stream>>>(hb, rowptr, csr, agg1b, N);
    sage_mfma<3><<<gemm_grid, 512, 0, stream>>>((const unsigned short*)hb,
                                                (const unsigned short*)agg1b, LDA1,
                                                Bb1, b1, x1b, N);

    // layer 2 (in place over x1b)
    gather_mean256<<<4096, 256, 0, stream>>>((const unsigned int*)x1b, rowptr, csr,
                                             (unsigned int*)agg2b, N);
    sage_mfma<8><<<gemm_grid, 512, 0, stream>>>(x1b, agg2b, OW, Bb2, b2, x1b, N);

    // per-graph mean pool + classifier
    pool_fc_kernel<<<G, 256, 0, stream>>>(x1b, gid, Wfc, bfc, out, N, NC);
}

// Round 9
// 448.634 us; speedup vs baseline: 1.2525x; 1.0257x over previous
//
#include <hip/hip_runtime.h>

#define WAVE 64
#define OW 256    // hidden width
#define LDA1 96   // padded layer-1 K (67 -> 96, zero pad)

typedef short bf16x8 __attribute__((ext_vector_type(8)));
typedef float f32x4  __attribute__((ext_vector_type(4)));

__device__ __forceinline__ unsigned short f2bf(float f) {   // RNE fp32 -> bf16
    unsigned int u = __float_as_uint(f);
    u = (u + 0x7FFF + ((u >> 16) & 1)) >> 16;
    return (unsigned short)u;
}
__device__ __forceinline__ float bf2f(unsigned short u) {
    return __uint_as_float(((unsigned int)u) << 16);
}
__device__ __forceinline__ float bflo(unsigned int u) { return __uint_as_float(u << 16); }
__device__ __forceinline__ float bfhi(unsigned int u) { return __uint_as_float(u & 0xFFFF0000u); }
__device__ __forceinline__ unsigned int packbf(float lo, float hi) {
    return (unsigned int)f2bf(lo) | ((unsigned int)f2bf(hi) << 16);
}
__device__ __forceinline__ float lrelu(float x) { return x > 0.0f ? x : 0.01f * x; }

// ---------------- fused prep: h->bf16, pack W1, pack W2, count dst (+rank) ----------------

__device__ __forceinline__ void pack_b_body(const float* __restrict__ Ws,
                                            const float* __restrict__ Wn,
                                            unsigned short* __restrict__ Bb,
                                            int KHALF, int KT_HALF, int idx) {
    int e  = idx & 7;
    int l  = (idx >> 3) & 63;
    int nt = (idx >> 9) & 15;
    int kt = idx >> 13;
    int n  = nt * 16 + (l & 15);
    int kh = (kt < KT_HALF ? kt : kt - KT_HALF) * 32 + (l >> 4) * 8 + e;
    const float* W = (kt < KT_HALF) ? Ws : Wn;
    float v = (kh < KHALF) ? W[(size_t)kh * OW + n] : 0.0f;
    Bb[idx] = f2bf(v);
}

__global__ void prep_kernel(const float* __restrict__ h, unsigned int* __restrict__ hb,
                            int N, int K,
                            const float* __restrict__ W1s, const float* __restrict__ W1n,
                            unsigned short* __restrict__ Bb1,
                            const float* __restrict__ W2s, const float* __restrict__ W2n,
                            unsigned short* __restrict__ Bb2,
                            const int* __restrict__ dst, int* __restrict__ cnt,
                            int* __restrict__ rank, int E) {
    const int tid = blockIdx.x * blockDim.x + threadIdx.x;
    const int nth = gridDim.x * blockDim.x;

    const int tot_h = N * (LDA1 / 2);
    for (int i = tid; i < tot_h; i += nth) {
        int row = i / (LDA1 / 2);
        int c   = (i - row * (LDA1 / 2)) * 2;
        float v0 = (c     < K) ? h[(size_t)row * K + c]     : 0.0f;
        float v1 = (c + 1 < K) ? h[(size_t)row * K + c + 1] : 0.0f;
        hb[i] = packbf(v0, v1);
    }
    for (int i = tid; i < 2 * 3 * 16 * 64 * 8; i += nth)
        pack_b_body(W1s, W1n, Bb1, K, 3, i);
    for (int i = tid; i < 2 * 8 * 16 * 64 * 8; i += nth)
        pack_b_body(W2s, W2n, Bb2, OW, 8, i);
    const int e4 = E >> 2;
    const int4* dst4 = (const int4*)dst;
    int4* rank4 = (int4*)rank;
    for (int i = tid; i < e4; i += nth) {
        int4 d = dst4[i];
        int4 r;
        r.x = atomicAdd(&cnt[d.x], 1);
        r.y = atomicAdd(&cnt[d.y], 1);
        r.z = atomicAdd(&cnt[d.z], 1);
        r.w = atomicAdd(&cnt[d.w], 1);
        rank4[i] = r;
    }
    for (int e = e4 * 4 + tid; e < E; e += nth)
        rank[e] = atomicAdd(&cnt[dst[e]], 1);
}

// ---------------- CSR scan ----------------

__global__ __launch_bounds__(1024) void scan_blocksum(const int* __restrict__ cnt,
                                                      int* __restrict__ bsum, int n) {
    __shared__ int s[1024];
    int i = blockIdx.x * 1024 + threadIdx.x;
    s[threadIdx.x] = (i < n) ? cnt[i] : 0;
    __syncthreads();
    for (int off = 512; off > 0; off >>= 1) {
        if (threadIdx.x < off) s[threadIdx.x] += s[threadIdx.x + off];
        __syncthreads();
    }
    if (threadIdx.x == 0) bsum[blockIdx.x] = s[0];
}

__global__ __launch_bounds__(128) void scan_offsets(int* __restrict__ bsum, int nb) {
    __shared__ int s[128];
    int v = (threadIdx.x < nb) ? bsum[threadIdx.x] : 0;
    s[threadIdx.x] = v;
    __syncthreads();
    for (int off = 1; off < 128; off <<= 1) {
        int t = (threadIdx.x >= off) ? s[threadIdx.x - off] : 0;
        __syncthreads();
        s[threadIdx.x] += t;
        __syncthreads();
    }
    if (threadIdx.x < nb) bsum[threadIdx.x] = s[threadIdx.x] - v;   // exclusive
}

__global__ __launch_bounds__(1024) void scan_write(const int* __restrict__ cnt,
                                                   const int* __restrict__ boff,
                                                   int* __restrict__ rowptr, int n) {
    __shared__ int s[1024];
    int i = blockIdx.x * 1024 + threadIdx.x;
    int v = (i < n) ? cnt[i] : 0;
    s[threadIdx.x] = v;
    __syncthreads();
    for (int off = 1; off < 1024; off <<= 1) {
        int t = (threadIdx.x >= off) ? s[threadIdx.x - off] : 0;
        __syncthreads();
        s[threadIdx.x] += t;
        __syncthreads();
    }
    if (i < n) rowptr[i + 1] = boff[blockIdx.x] + s[threadIdx.x];
    if (i == 0) rowptr[0] = 0;
}

// atomic-free fill: pos = rowptr[dst] + rank
__global__ void fill_kernel(const int* __restrict__ src, const int* __restrict__ dst,
                            const int* __restrict__ rank, const int* __restrict__ rowptr,
                            int* __restrict__ csr_src, int E) {
    const int tid = blockIdx.x * blockDim.x + threadIdx.x;
    const int nth = gridDim.x * blockDim.x;
    const int e4 = E >> 2;
    const int4* dst4 = (const int4*)dst;
    const int4* src4 = (const int4*)src;
    const int4* rank4 = (const int4*)rank;
    for (int i = tid; i < e4; i += nth) {
        int4 d = dst4[i];
        int4 s = src4[i];
        int4 r = rank4[i];
        csr_src[rowptr[d.x] + r.x] = s.x;
        csr_src[rowptr[d.y] + r.y] = s.y;
        csr_src[rowptr[d.z] + r.z] = s.z;
        csr_src[rowptr[d.w] + r.w] = s.w;
    }
    for (int e = e4 * 4 + tid; e < E; e += nth)
        csr_src[rowptr[dst[e]] + rank[e]] = src[e];
}

// ---------------- gathers (neighbor MEAN, atomic-free) ----------------

// layer-2 gather, COLUMN-SPLIT: one pass covers 128 of 256 cols (half-row = 256 B).
// Wave = 4 independent 16-lane groups, each with its own edge stream; 2-deep unroll.
// Working set per pass = N*256B = 25.6 MB -> better per-XCD L2 survival.
__global__ void gather_mean256_half(const unsigned int* __restrict__ feat,
                                    const int* __restrict__ rowptr, const int* __restrict__ csr,
                                    unsigned int* __restrict__ aggm, int N, int colhalf) {
    const int lane = threadIdx.x & (WAVE - 1);
    const int grp  = lane >> 4;          // 0..3
    const int sub  = lane & 15;          // uint4 slot within half-row
    const int cb   = colhalf * 64;       // uint offset of column half
    int wave = (blockIdx.x * blockDim.x + threadIdx.x) / WAVE;
    int nw   = (gridDim.x * blockDim.x) / WAVE;

    for (int v = wave; v < N; v += nw) {
        const int beg = rowptr[v], deg = rowptr[v + 1] - beg;
        float l0 = 0.f, h0 = 0.f, l1 = 0.f, h1 = 0.f,
              l2 = 0.f, h2 = 0.f, l3 = 0.f, h3 = 0.f;

        const int noct = deg >> 3;           // each iter consumes 8 edges (4 grp x 2)
        for (int i = 0; i < noct; ++i) {
            int e0 = csr[beg + 8 * i + grp];
            int e1 = csr[beg + 8 * i + 4 + grp];
            uint4 x0 = *(const uint4*)(feat + (size_t)e0 * 128 + cb + sub * 4);
            uint4 x1 = *(const uint4*)(feat + (size_t)e1 * 128 + cb + sub * 4);
            l0 += bflo(x0.x) + bflo(x1.x); h0 += bfhi(x0.x) + bfhi(x1.x);
            l1 += bflo(x0.y) + bflo(x1.y); h1 += bfhi(x0.y) + bfhi(x1.y);
            l2 += bflo(x0.z) + bflo(x1.z); h2 += bfhi(x0.z) + bfhi(x1.z);
            l3 += bflo(x0.w) + bflo(x1.w); h3 += bfhi(x0.w) + bfhi(x1.w);
        }
        for (int e = (noct << 3) + grp; e < deg; e += 4) {   // tail, per-group
            int s = csr[beg + e];
            uint4 x = *(const uint4*)(feat + (size_t)s * 128 + cb + sub * 4);
            l0 += bflo(x.x); h0 += bfhi(x.x);
            l1 += bflo(x.y); h1 += bfhi(x.y);
            l2 += bflo(x.z); h2 += bfhi(x.z);
            l3 += bflo(x.w); h3 += bfhi(x.w);
        }
        // combine the 4 groups (xor-16 then xor-32)
        l0 += __shfl_xor(l0, 16); l0 += __shfl_xor(l0, 32);
        h0 += __shfl_xor(h0, 16); h0 += __shfl_xor(h0, 32);
        l1 += __shfl_xor(l1, 16); l1 += __shfl_xor(l1, 32);
        h1 += __shfl_xor(h1, 16); h1 += __shfl_xor(h1, 32);
        l2 += __shfl_xor(l2, 16); l2 += __shfl_xor(l2, 32);
        h2 += __shfl_xor(h2, 16); h2 += __shfl_xor(h2, 32);
        l3 += __shfl_xor(l3, 16); l3 += __shfl_xor(l3, 32);
        h3 += __shfl_xor(h3, 16); h3 += __shfl_xor(h3, 32);

        if (grp == 0) {
            float inv = 1.0f / fmaxf((float)deg, 1.0f);
            uint4 o;
            o.x = packbf(l0 * inv, h0 * inv);
            o.y = packbf(l1 * inv, h1 * inv);
            o.z = packbf(l2 * inv, h2 * inv);
            o.w = packbf(l3 * inv, h3 * inv);
            *(uint4*)(aggm + (size_t)v * 128 + cb + sub * 4) = o;
        }
    }
}

// layer-1 gather: rows of 96 bf16 (192 B = 48 uints); split-half wave, uint2/lane
__global__ void gather_mean_pad(const unsigned int* __restrict__ feat,
                                const int* __restrict__ rowptr, const int* __restrict__ csr,
                                unsigned int* __restrict__ aggm, int N) {
    const int lane = threadIdx.x & (WAVE - 1);
    const int half = lane >> 5;
    const int sub  = lane & 31;
    const bool act = sub < 24;
    int wave = (blockIdx.x * blockDim.x + threadIdx.x) / WAVE;
    int nw   = (gridDim.x * blockDim.x) / WAVE;

    for (int v = wave; v < N; v += nw) {
        const int beg = rowptr[v], deg = rowptr[v + 1] - beg;
        const int npairs = deg >> 1;
        float l0 = 0.f, h0 = 0.f, l1 = 0.f, h1 = 0.f;

        int p = 0;
        for (; p + 3 < npairs; p += 4) {
            int i0 = csr[beg + 2 * (p + 0) + half];
            int i1 = csr[beg + 2 * (p + 1) + half];
            int i2 = csr[beg + 2 * (p + 2) + half];
            int i3 = csr[beg + 2 * (p + 3) + half];
            if (act) {
                uint2 x0 = *(const uint2*)(feat + (size_t)i0 * 48 + sub * 2);
                uint2 x1 = *(const uint2*)(feat + (size_t)i1 * 48 + sub * 2);
                uint2 x2 = *(const uint2*)(feat + (size_t)i2 * 48 + sub * 2);
                uint2 x3 = *(const uint2*)(feat + (size_t)i3 * 48 + sub * 2);
                l0 += bflo(x0.x) + bflo(x1.x) + bflo(x2.x) + bflo(x3.x);
                h0 += bfhi(x0.x) + bfhi(x1.x) + bfhi(x2.x) + bfhi(x3.x);
                l1 += bflo(x0.y) + bflo(x1.y) + bflo(x2.y) + bflo(x3.y);
                h1 += bfhi(x0.y) + bfhi(x1.y) + bfhi(x2.y) + bfhi(x3.y);
            }
        }
        for (; p < npairs; ++p) {
            int i0 = csr[beg + 2 * p + half];
            if (act) {
                uint2 x0 = *(const uint2*)(feat + (size_t)i0 * 48 + sub * 2);
                l0 += bflo(x0.x); h0 += bfhi(x0.x);
                l1 += bflo(x0.y); h1 += bfhi(x0.y);
            }
        }
        if ((deg & 1) && half == 0) {
            int i0 = csr[beg + deg - 1];
            if (act) {
                uint2 x0 = *(const uint2*)(feat + (size_t)i0 * 48 + sub * 2);
                l0 += bflo(x0.x); h0 += bfhi(x0.x);
                l1 += bflo(x0.y); h1 += bfhi(x0.y);
            }
        }
        l0 += __shfl_xor(l0, 32); h0 += __shfl_xor(h0, 32);
        l1 += __shfl_xor(l1, 32); h1 += __shfl_xor(h1, 32);

        if (half == 0 && act) {
            float inv = 1.0f / fmaxf((float)deg, 1.0f);
            uint2 o;
            o.x = packbf(l0 * inv, h0 * inv);
            o.y = packbf(l1 * inv, h1 * inv);
            *(uint2*)(aggm + (size_t)v * 48 + sub * 2) = o;
        }
    }
}

// ---------------- MFMA SAGE GEMM (LDS-free, barrier-free, bf16 A) ----------------
template<int KT_HALF>
__global__ __launch_bounds__(512) void sage_mfma(
    const unsigned short* __restrict__ Hs, const unsigned short* __restrict__ Hn, int lda,
    const unsigned short* __restrict__ Bb, const float* __restrict__ bias,
    unsigned short* __restrict__ outb, int M)
{
    const int t    = threadIdx.x;
    const int lane = t & 63, wid = t >> 6;
    const int wm   = wid >> 1, wn = wid & 1;
    const int brow = blockIdx.x * 128;
    const int lrow = lane & 15, kblk = lane >> 4;

    const int r0 = brow + wm * 32 + lrow;
    const int r1 = r0 + 16;
    const int r0c = (r0 < M) ? r0 : (M - 1);
    const int r1c = (r1 < M) ? r1 : (M - 1);

    f32x4 acc[2][8];
#pragma unroll
    for (int rt = 0; rt < 2; ++rt)
#pragma unroll
        for (int ct = 0; ct < 8; ++ct) acc[rt][ct] = (f32x4)0.0f;

    const int NT = 2 * KT_HALF;
#pragma unroll 4
    for (int kt = 0; kt < NT; ++kt) {
        const bool self = kt < KT_HALF;
        const int  kh   = (self ? kt : kt - KT_HALF) * 32 + kblk * 8;
        const unsigned short* src = self ? Hs : Hn;
        bf16x8 a0 = *(const bf16x8*)(src + (size_t)r0c * lda + kh);
        bf16x8 a1 = *(const bf16x8*)(src + (size_t)r1c * lda + kh);
        const unsigned short* bp = Bb + (((size_t)kt * 16 + wn * 8) * 64 + lane) * 8;
#pragma unroll
        for (int ct = 0; ct < 8; ++ct) {
            bf16x8 b = *(const bf16x8*)(bp + (size_t)ct * 64 * 8);
            acc[0][ct] = __builtin_amdgcn_mfma_f32_16x16x32_bf16(a0, b, acc[0][ct], 0, 0, 0);
            acc[1][ct] = __builtin_amdgcn_mfma_f32_16x16x32_bf16(a1, b, acc[1][ct], 0, 0, 0);
        }
    }

    // D layout: col=lane&15, row=(lane>>4)*4+j
#pragma unroll
    for (int rt = 0; rt < 2; ++rt) {
        int rbase = brow + wm * 32 + rt * 16 + kblk * 4;
#pragma unroll
        for (int ct = 0; ct < 8; ++ct) {
            int col = wn * 128 + ct * 16 + lrow;
            float vb = bias[col];
#pragma unroll
            for (int j = 0; j < 4; ++j) {
                int row = rbase + j;
                if (row < M)
                    outb[(size_t)row * OW + col] = f2bf(lrelu(acc[rt][ct][j] + vb));
            }
        }
    }
}

// ---------------- per-graph mean pool + FC (graph_ids sorted) ----------------

__global__ __launch_bounds__(256) void pool_fc_kernel(
    const unsigned short* __restrict__ x, const int* __restrict__ gid,
    const float* __restrict__ Wfc, const float* __restrict__ bfc,
    float* __restrict__ out, int N, int C)
{
    int g = blockIdx.x;
    int lo = 0, hi = N;
    while (lo < hi) { int m = (lo + hi) >> 1; if (gid[m] < g) lo = m + 1; else hi = m; }
    int beg = lo;
    hi = N;
    while (lo < hi) { int m = (lo + hi) >> 1; if (gid[m] <= g) lo = m + 1; else hi = m; }
    int end = lo;

    __shared__ float hg[OW];
    int c = threadIdx.x;
    float s0 = 0.f, s1 = 0.f, s2 = 0.f, s3 = 0.f;
    int r = beg;
    for (; r + 3 < end; r += 4) {
        s0 += bf2f(x[(size_t)(r + 0) * OW + c]);
        s1 += bf2f(x[(size_t)(r + 1) * OW + c]);
        s2 += bf2f(x[(size_t)(r + 2) * OW + c]);
        s3 += bf2f(x[(size_t)(r + 3) * OW + c]);
    }
    for (; r < end; ++r) s0 += bf2f(x[(size_t)r * OW + c]);
    float s = (s0 + s1) + (s2 + s3);
    float inv = (end > beg) ? 1.0f / (float)(end - beg) : 0.0f;
    hg[c] = s * inv;
    __syncthreads();

    if (c < C) {
        float a = bfc[c];
        for (int k = 0; k < OW; ++k)
            a = fmaf(hg[k], Wfc[(size_t)k * C + c], a);
        out[(size_t)g * C + c] = a;
    }
}

extern "C" void kernel_launch(void* const* d_in, const int* in_sizes, int n_in,
                              void* d_out, int out_size, void* d_ws, size_t ws_size,
                              hipStream_t stream) {
    const float* h   = (const float*)d_in[0];
    const float* W1s = (const float*)d_in[1];
    const float* W1n = (const float*)d_in[2];
    const float* b1  = (const float*)d_in[3];
    const float* W2s = (const float*)d_in[4];
    const float* W2n = (const float*)d_in[5];
    const float* b2  = (const float*)d_in[6];
    const float* Wfc = (const float*)d_in[7];
    const float* bfc = (const float*)d_in[8];
    const int*   src = (const int*)d_in[9];
    const int*   dst = (const int*)d_in[10];
    const int*   gid = (const int*)d_in[11];

    const int N  = in_sizes[11];          // 100000
    const int E  = in_sizes[9];           // 1600000
    const int K1 = in_sizes[0] / N;       // 67
    const int NC = in_sizes[8];           // 18
    const int G  = out_size / NC;         // 256

    char* w = (char*)d_ws;
    auto alloc = [&](size_t bytes) { char* p = w; w += (bytes + 255) & ~(size_t)255; return p; };
    unsigned int*   hb     = (unsigned int*)alloc((size_t)N * (LDA1 / 2) * 4);
    unsigned int*   agg1b  = (unsigned int*)alloc((size_t)N * (LDA1 / 2) * 4);
    unsigned short* x1b    = (unsigned short*)alloc((size_t)N * OW * 2);
    unsigned short* agg2b  = (unsigned short*)alloc((size_t)N * OW * 2);
    int*            rowptr = (int*)alloc((size_t)(N + 1) * 4);
    int*            cnt    = (int*)alloc((size_t)N * 4);
    int*            csr    = (int*)alloc((size_t)E * 4);
    int*            rank   = (int*)alloc((size_t)E * 4);
    int*            bsum   = (int*)alloc(1024 * 4);
    unsigned short* Bb1    = (unsigned short*)alloc((size_t)2 * 3 * 16 * 64 * 8 * 2);
    unsigned short* Bb2    = (unsigned short*)alloc((size_t)2 * 8 * 16 * 64 * 8 * 2);

    float* out = (float*)d_out;
    const int nb = (N + 1023) / 1024;

    // fused prep: h->bf16, pack W1/W2, count dst + per-edge rank
    hipMemsetAsync(cnt, 0, (size_t)N * sizeof(int), stream);
    prep_kernel<<<2048, 256, 0, stream>>>(h, hb, N, K1, W1s, W1n, Bb1, W2s, W2n, Bb2,
                                          dst, cnt, rank, E);

    // CSR scan + atomic-free fill
    scan_blocksum<<<nb, 1024, 0, stream>>>(cnt, bsum, N);
    scan_offsets<<<1, 128, 0, stream>>>(bsum, nb);
    scan_write<<<nb, 1024, 0, stream>>>(cnt, bsum, rowptr, N);
    fill_kernel<<<2048, 256, 0, stream>>>(src, dst, rank, rowptr, csr, E);

    const int gemm_grid = (N + 127) / 128;

    // layer 1
    gather_mean_pad<<<4096, 256, 0, stream>>>(hb, rowptr, csr, agg1b, N);
    sage_mfma<3><<<gemm_grid, 512, 0, stream>>>((const unsigned short*)hb,
                                                (const unsigned short*)agg1b, LDA1,
                                                Bb1, b1, x1b, N);

    // layer 2: column-split gather (two half-width passes), then in-place GEMM
    gather_mean256_half<<<4096, 256, 0, stream>>>((const unsigned int*)x1b, rowptr, csr,
                                                  (unsigned int*)agg2b, N, 0);
    gather_mean256_half<<<4096, 256, 0, stream>>>((const unsigned int*)x1b, rowptr, csr,
                                                  (unsigned int*)agg2b, N, 1);
    sage_mfma<8><<<gemm_grid, 512, 0, stream>>>(x1b, agg2b, OW, Bb2, b2, x1b, N);

    // per-graph mean pool + classifier
    pool_fc_kernel<<<G, 256, 0, stream>>>(x1b, gid, Wfc, bfc, out, N, NC);
}

// Round 10
// 441.934 us; speedup vs baseline: 1.2715x; 1.0152x over previous
//
#include <hip/hip_runtime.h>

#define WAVE 64
#define OW 256    // hidden width
#define LDA1 96   // padded layer-1 K (67 -> 96, zero pad)

typedef short bf16x8 __attribute__((ext_vector_type(8)));
typedef float f32x4  __attribute__((ext_vector_type(4)));

__device__ __forceinline__ unsigned short f2bf(float f) {   // RNE fp32 -> bf16
    unsigned int u = __float_as_uint(f);
    u = (u + 0x7FFF + ((u >> 16) & 1)) >> 16;
    return (unsigned short)u;
}
__device__ __forceinline__ float bf2f(unsigned short u) {
    return __uint_as_float(((unsigned int)u) << 16);
}
__device__ __forceinline__ float bflo(unsigned int u) { return __uint_as_float(u << 16); }
__device__ __forceinline__ float bfhi(unsigned int u) { return __uint_as_float(u & 0xFFFF0000u); }
__device__ __forceinline__ unsigned int packbf(float lo, float hi) {
    return (unsigned int)f2bf(lo) | ((unsigned int)f2bf(hi) << 16);
}
__device__ __forceinline__ float lrelu(float x) { return x > 0.0f ? x : 0.01f * x; }

// ---------------- fused prep: h->bf16, pack W1, pack W2, count dst (+rank) ----------------

__device__ __forceinline__ void pack_b_body(const float* __restrict__ Ws,
                                            const float* __restrict__ Wn,
                                            unsigned short* __restrict__ Bb,
                                            int KHALF, int KT_HALF, int idx) {
    int e  = idx & 7;
    int l  = (idx >> 3) & 63;
    int nt = (idx >> 9) & 15;
    int kt = idx >> 13;
    int n  = nt * 16 + (l & 15);
    int kh = (kt < KT_HALF ? kt : kt - KT_HALF) * 32 + (l >> 4) * 8 + e;
    const float* W = (kt < KT_HALF) ? Ws : Wn;
    float v = (kh < KHALF) ? W[(size_t)kh * OW + n] : 0.0f;
    Bb[idx] = f2bf(v);
}

__global__ void prep_kernel(const float* __restrict__ h, unsigned int* __restrict__ hb,
                            int N, int K,
                            const float* __restrict__ W1s, const float* __restrict__ W1n,
                            unsigned short* __restrict__ Bb1,
                            const float* __restrict__ W2s, const float* __restrict__ W2n,
                            unsigned short* __restrict__ Bb2,
                            const int* __restrict__ dst, int* __restrict__ cnt,
                            int* __restrict__ rank, int E) {
    const int tid = blockIdx.x * blockDim.x + threadIdx.x;
    const int nth = gridDim.x * blockDim.x;

    const int tot_h = N * (LDA1 / 2);
    for (int i = tid; i < tot_h; i += nth) {
        int row = i / (LDA1 / 2);
        int c   = (i - row * (LDA1 / 2)) * 2;
        float v0 = (c     < K) ? h[(size_t)row * K + c]     : 0.0f;
        float v1 = (c + 1 < K) ? h[(size_t)row * K + c + 1] : 0.0f;
        hb[i] = packbf(v0, v1);
    }
    for (int i = tid; i < 2 * 3 * 16 * 64 * 8; i += nth)
        pack_b_body(W1s, W1n, Bb1, K, 3, i);
    for (int i = tid; i < 2 * 8 * 16 * 64 * 8; i += nth)
        pack_b_body(W2s, W2n, Bb2, OW, 8, i);
    const int e4 = E >> 2;
    const int4* dst4 = (const int4*)dst;
    int4* rank4 = (int4*)rank;
    for (int i = tid; i < e4; i += nth) {
        int4 d = dst4[i];
        int4 r;
        r.x = atomicAdd(&cnt[d.x], 1);
        r.y = atomicAdd(&cnt[d.y], 1);
        r.z = atomicAdd(&cnt[d.z], 1);
        r.w = atomicAdd(&cnt[d.w], 1);
        rank4[i] = r;
    }
    for (int e = e4 * 4 + tid; e < E; e += nth)
        rank[e] = atomicAdd(&cnt[dst[e]], 1);
}

// ---------------- CSR scan ----------------

__global__ __launch_bounds__(1024) void scan_blocksum(const int* __restrict__ cnt,
                                                      int* __restrict__ bsum, int n) {
    __shared__ int s[1024];
    int i = blockIdx.x * 1024 + threadIdx.x;
    s[threadIdx.x] = (i < n) ? cnt[i] : 0;
    __syncthreads();
    for (int off = 512; off > 0; off >>= 1) {
        if (threadIdx.x < off) s[threadIdx.x] += s[threadIdx.x + off];
        __syncthreads();
    }
    if (threadIdx.x == 0) bsum[blockIdx.x] = s[0];
}

__global__ __launch_bounds__(128) void scan_offsets(int* __restrict__ bsum, int nb) {
    __shared__ int s[128];
    int v = (threadIdx.x < nb) ? bsum[threadIdx.x] : 0;
    s[threadIdx.x] = v;
    __syncthreads();
    for (int off = 1; off < 128; off <<= 1) {
        int t = (threadIdx.x >= off) ? s[threadIdx.x - off] : 0;
        __syncthreads();
        s[threadIdx.x] += t;
        __syncthreads();
    }
    if (threadIdx.x < nb) bsum[threadIdx.x] = s[threadIdx.x] - v;   // exclusive
}

__global__ __launch_bounds__(1024) void scan_write(const int* __restrict__ cnt,
                                                   const int* __restrict__ boff,
                                                   int* __restrict__ rowptr, int n) {
    __shared__ int s[1024];
    int i = blockIdx.x * 1024 + threadIdx.x;
    int v = (i < n) ? cnt[i] : 0;
    s[threadIdx.x] = v;
    __syncthreads();
    for (int off = 1; off < 1024; off <<= 1) {
        int t = (threadIdx.x >= off) ? s[threadIdx.x - off] : 0;
        __syncthreads();
        s[threadIdx.x] += t;
        __syncthreads();
    }
    if (i < n) rowptr[i + 1] = boff[blockIdx.x] + s[threadIdx.x];
    if (i == 0) rowptr[0] = 0;
}

// atomic-free fill: pos = rowptr[dst] + rank
__global__ void fill_kernel(const int* __restrict__ src, const int* __restrict__ dst,
                            const int* __restrict__ rank, const int* __restrict__ rowptr,
                            int* __restrict__ csr_src, int E) {
    const int tid = blockIdx.x * blockDim.x + threadIdx.x;
    const int nth = gridDim.x * blockDim.x;
    const int e4 = E >> 2;
    const int4* dst4 = (const int4*)dst;
    const int4* src4 = (const int4*)src;
    const int4* rank4 = (const int4*)rank;
    for (int i = tid; i < e4; i += nth) {
        int4 d = dst4[i];
        int4 s = src4[i];
        int4 r = rank4[i];
        csr_src[rowptr[d.x] + r.x] = s.x;
        csr_src[rowptr[d.y] + r.y] = s.y;
        csr_src[rowptr[d.z] + r.z] = s.z;
        csr_src[rowptr[d.w] + r.w] = s.w;
    }
    for (int e = e4 * 4 + tid; e < E; e += nth)
        csr_src[rowptr[dst[e]] + rank[e]] = src[e];
}

// ---------------- gathers (neighbor MEAN, atomic-free) ----------------

// layer-2 gather, COLUMN-SPLIT: one pass covers 128 of 256 cols (half-row = 256 B).
__global__ void gather_mean256_half(const unsigned int* __restrict__ feat,
                                    const int* __restrict__ rowptr, const int* __restrict__ csr,
                                    unsigned int* __restrict__ aggm, int N, int colhalf) {
    const int lane = threadIdx.x & (WAVE - 1);
    const int grp  = lane >> 4;          // 0..3
    const int sub  = lane & 15;          // uint4 slot within half-row
    const int cb   = colhalf * 64;       // uint offset of column half
    int wave = (blockIdx.x * blockDim.x + threadIdx.x) / WAVE;
    int nw   = (gridDim.x * blockDim.x) / WAVE;

    for (int v = wave; v < N; v += nw) {
        const int beg = rowptr[v], deg = rowptr[v + 1] - beg;
        float l0 = 0.f, h0 = 0.f, l1 = 0.f, h1 = 0.f,
              l2 = 0.f, h2 = 0.f, l3 = 0.f, h3 = 0.f;

        const int noct = deg >> 3;           // each iter consumes 8 edges (4 grp x 2)
        for (int i = 0; i < noct; ++i) {
            int e0 = csr[beg + 8 * i + grp];
            int e1 = csr[beg + 8 * i + 4 + grp];
            uint4 x0 = *(const uint4*)(feat + (size_t)e0 * 128 + cb + sub * 4);
            uint4 x1 = *(const uint4*)(feat + (size_t)e1 * 128 + cb + sub * 4);
            l0 += bflo(x0.x) + bflo(x1.x); h0 += bfhi(x0.x) + bfhi(x1.x);
            l1 += bflo(x0.y) + bflo(x1.y); h1 += bfhi(x0.y) + bfhi(x1.y);
            l2 += bflo(x0.z) + bflo(x1.z); h2 += bfhi(x0.z) + bfhi(x1.z);
            l3 += bflo(x0.w) + bflo(x1.w); h3 += bfhi(x0.w) + bfhi(x1.w);
        }
        for (int e = (noct << 3) + grp; e < deg; e += 4) {   // tail, per-group
            int s = csr[beg + e];
            uint4 x = *(const uint4*)(feat + (size_t)s * 128 + cb + sub * 4);
            l0 += bflo(x.x); h0 += bfhi(x.x);
            l1 += bflo(x.y); h1 += bfhi(x.y);
            l2 += bflo(x.z); h2 += bfhi(x.z);
            l3 += bflo(x.w); h3 += bfhi(x.w);
        }
        // combine the 4 groups (xor-16 then xor-32)
        l0 += __shfl_xor(l0, 16); l0 += __shfl_xor(l0, 32);
        h0 += __shfl_xor(h0, 16); h0 += __shfl_xor(h0, 32);
        l1 += __shfl_xor(l1, 16); l1 += __shfl_xor(l1, 32);
        h1 += __shfl_xor(h1, 16); h1 += __shfl_xor(h1, 32);
        l2 += __shfl_xor(l2, 16); l2 += __shfl_xor(l2, 32);
        h2 += __shfl_xor(h2, 16); h2 += __shfl_xor(h2, 32);
        l3 += __shfl_xor(l3, 16); l3 += __shfl_xor(l3, 32);
        h3 += __shfl_xor(h3, 16); h3 += __shfl_xor(h3, 32);

        if (grp == 0) {
            float inv = 1.0f / fmaxf((float)deg, 1.0f);
            uint4 o;
            o.x = packbf(l0 * inv, h0 * inv);
            o.y = packbf(l1 * inv, h1 * inv);
            o.z = packbf(l2 * inv, h2 * inv);
            o.w = packbf(l3 * inv, h3 * inv);
            *(uint4*)(aggm + (size_t)v * 128 + cb + sub * 4) = o;
        }
    }
}

// layer-1 gather: rows of 96 bf16 (192 B = 48 uints); split-half wave, uint2/lane
__global__ void gather_mean_pad(const unsigned int* __restrict__ feat,
                                const int* __restrict__ rowptr, const int* __restrict__ csr,
                                unsigned int* __restrict__ aggm, int N) {
    const int lane = threadIdx.x & (WAVE - 1);
    const int half = lane >> 5;
    const int sub  = lane & 31;
    const bool act = sub < 24;
    int wave = (blockIdx.x * blockDim.x + threadIdx.x) / WAVE;
    int nw   = (gridDim.x * blockDim.x) / WAVE;

    for (int v = wave; v < N; v += nw) {
        const int beg = rowptr[v], deg = rowptr[v + 1] - beg;
        const int npairs = deg >> 1;
        float l0 = 0.f, h0 = 0.f, l1 = 0.f, h1 = 0.f;

        int p = 0;
        for (; p + 3 < npairs; p += 4) {
            int i0 = csr[beg + 2 * (p + 0) + half];
            int i1 = csr[beg + 2 * (p + 1) + half];
            int i2 = csr[beg + 2 * (p + 2) + half];
            int i3 = csr[beg + 2 * (p + 3) + half];
            if (act) {
                uint2 x0 = *(const uint2*)(feat + (size_t)i0 * 48 + sub * 2);
                uint2 x1 = *(const uint2*)(feat + (size_t)i1 * 48 + sub * 2);
                uint2 x2 = *(const uint2*)(feat + (size_t)i2 * 48 + sub * 2);
                uint2 x3 = *(const uint2*)(feat + (size_t)i3 * 48 + sub * 2);
                l0 += bflo(x0.x) + bflo(x1.x) + bflo(x2.x) + bflo(x3.x);
                h0 += bfhi(x0.x) + bfhi(x1.x) + bfhi(x2.x) + bfhi(x3.x);
                l1 += bflo(x0.y) + bflo(x1.y) + bflo(x2.y) + bflo(x3.y);
                h1 += bfhi(x0.y) + bfhi(x1.y) + bfhi(x2.y) + bfhi(x3.y);
            }
        }
        for (; p < npairs; ++p) {
            int i0 = csr[beg + 2 * p + half];
            if (act) {
                uint2 x0 = *(const uint2*)(feat + (size_t)i0 * 48 + sub * 2);
                l0 += bflo(x0.x); h0 += bfhi(x0.x);
                l1 += bflo(x0.y); h1 += bfhi(x0.y);
            }
        }
        if ((deg & 1) && half == 0) {
            int i0 = csr[beg + deg - 1];
            if (act) {
                uint2 x0 = *(const uint2*)(feat + (size_t)i0 * 48 + sub * 2);
                l0 += bflo(x0.x); h0 += bfhi(x0.x);
                l1 += bflo(x0.y); h1 += bfhi(x0.y);
            }
        }
        l0 += __shfl_xor(l0, 32); h0 += __shfl_xor(h0, 32);
        l1 += __shfl_xor(l1, 32); h1 += __shfl_xor(h1, 32);

        if (half == 0 && act) {
            float inv = 1.0f / fmaxf((float)deg, 1.0f);
            uint2 o;
            o.x = packbf(l0 * inv, h0 * inv);
            o.y = packbf(l1 * inv, h1 * inv);
            *(uint2*)(aggm + (size_t)v * 48 + sub * 2) = o;
        }
    }
}

// ---------------- MFMA SAGE GEMM (LDS-staged B, register-prefetched A) ----------------
// out = lrelu( [Hs | Hn] @ Bb + bias ), bf16 out [M][256]; rows block-owned -> in-place ok.
// K-loop split into chunks of CHUNK kt; per chunk: prefetch A frags to regs, stage the
// B chunk to LDS (coalesced bf16x8, conflict-free), then MFMAs read B via ds_read_b128.
template<int KT_HALF, int CHUNK>
__global__ __launch_bounds__(512) void sage_mfma(
    const unsigned short* __restrict__ Hs, const unsigned short* __restrict__ Hn, int lda,
    const unsigned short* __restrict__ Bb, const float* __restrict__ bias,
    unsigned short* __restrict__ outb, int M)
{
    constexpr int NT    = 2 * KT_HALF;
    constexpr int NCH   = NT / CHUNK;
    constexpr int CELEM = CHUNK * 16 * 64;           // bf16x8 elems per chunk
    constexpr int CPT   = CELEM / 512;               // per-thread stage count
    __shared__ bf16x8 Bs[CELEM];                     // CHUNK=4 -> 64 KB

    const int t    = threadIdx.x;
    const int lane = t & 63, wid = t >> 6;
    const int wm   = wid >> 1, wn = wid & 1;
    const int brow = blockIdx.x * 128;
    const int lrow = lane & 15, kblk = lane >> 4;

    const int r0 = brow + wm * 32 + lrow;
    const int r1 = r0 + 16;
    const int r0c = (r0 < M) ? r0 : (M - 1);
    const int r1c = (r1 < M) ? r1 : (M - 1);

    f32x4 acc[2][8];
#pragma unroll
    for (int rt = 0; rt < 2; ++rt)
#pragma unroll
        for (int ct = 0; ct < 8; ++ct) acc[rt][ct] = (f32x4)0.0f;

    for (int ch = 0; ch < NCH; ++ch) {
        // A register prefetch for the whole chunk (independent global loads)
        bf16x8 a0[CHUNK], a1[CHUNK];
#pragma unroll
        for (int k = 0; k < CHUNK; ++k) {
            int kt = ch * CHUNK + k;
            bool self = kt < KT_HALF;
            int kh = (self ? kt : kt - KT_HALF) * 32 + kblk * 8;
            const unsigned short* srcp = self ? Hs : Hn;
            a0[k] = *(const bf16x8*)(srcp + (size_t)r0c * lda + kh);
            a1[k] = *(const bf16x8*)(srcp + (size_t)r1c * lda + kh);
        }
        // B chunk stage: global -> regs -> LDS (coalesced both sides)
        const bf16x8* gB = (const bf16x8*)Bb + (size_t)ch * CELEM;
        bf16x8 tmp[CPT];
#pragma unroll
        for (int i = 0; i < CPT; ++i) tmp[i] = gB[i * 512 + t];
        __syncthreads();                 // previous chunk's reads complete
#pragma unroll
        for (int i = 0; i < CPT; ++i) Bs[i * 512 + t] = tmp[i];
        __syncthreads();                 // chunk visible to all waves
        // compute
#pragma unroll
        for (int k = 0; k < CHUNK; ++k) {
            const bf16x8* bp = &Bs[(k * 16 + wn * 8) * 64 + lane];
#pragma unroll
            for (int ct = 0; ct < 8; ++ct) {
                bf16x8 b = bp[ct * 64];
                acc[0][ct] = __builtin_amdgcn_mfma_f32_16x16x32_bf16(a0[k], b, acc[0][ct], 0, 0, 0);
                acc[1][ct] = __builtin_amdgcn_mfma_f32_16x16x32_bf16(a1[k], b, acc[1][ct], 0, 0, 0);
            }
        }
    }

    // D layout: col=lane&15, row=(lane>>4)*4+j
#pragma unroll
    for (int rt = 0; rt < 2; ++rt) {
        int rbase = brow + wm * 32 + rt * 16 + kblk * 4;
#pragma unroll
        for (int ct = 0; ct < 8; ++ct) {
            int col = wn * 128 + ct * 16 + lrow;
            float vb = bias[col];
#pragma unroll
            for (int j = 0; j < 4; ++j) {
                int row = rbase + j;
                if (row < M)
                    outb[(size_t)row * OW + col] = f2bf(lrelu(acc[rt][ct][j] + vb));
            }
        }
    }
}

// ---------------- per-graph mean pool + FC (graph_ids sorted) ----------------

__global__ __launch_bounds__(256) void pool_fc_kernel(
    const unsigned short* __restrict__ x, const int* __restrict__ gid,
    const float* __restrict__ Wfc, const float* __restrict__ bfc,
    float* __restrict__ out, int N, int C)
{
    int g = blockIdx.x;
    int lo = 0, hi = N;
    while (lo < hi) { int m = (lo + hi) >> 1; if (gid[m] < g) lo = m + 1; else hi = m; }
    int beg = lo;
    hi = N;
    while (lo < hi) { int m = (lo + hi) >> 1; if (gid[m] <= g) lo = m + 1; else hi = m; }
    int end = lo;

    __shared__ float hg[OW];
    int c = threadIdx.x;
    float s0 = 0.f, s1 = 0.f, s2 = 0.f, s3 = 0.f;
    int r = beg;
    for (; r + 3 < end; r += 4) {
        s0 += bf2f(x[(size_t)(r + 0) * OW + c]);
        s1 += bf2f(x[(size_t)(r + 1) * OW + c]);
        s2 += bf2f(x[(size_t)(r + 2) * OW + c]);
        s3 += bf2f(x[(size_t)(r + 3) * OW + c]);
    }
    for (; r < end; ++r) s0 += bf2f(x[(size_t)r * OW + c]);
    float s = (s0 + s1) + (s2 + s3);
    float inv = (end > beg) ? 1.0f / (float)(end - beg) : 0.0f;
    hg[c] = s * inv;
    __syncthreads();

    if (c < C) {
        float a = bfc[c];
        for (int k = 0; k < OW; ++k)
            a = fmaf(hg[k], Wfc[(size_t)k * C + c], a);
        out[(size_t)g * C + c] = a;
    }
}

extern "C" void kernel_launch(void* const* d_in, const int* in_sizes, int n_in,
                              void* d_out, int out_size, void* d_ws, size_t ws_size,
                              hipStream_t stream) {
    const float* h   = (const float*)d_in[0];
    const float* W1s = (const float*)d_in[1];
    const float* W1n = (const float*)d_in[2];
    const float* b1  = (const float*)d_in[3];
    const float* W2s = (const float*)d_in[4];
    const float* W2n = (const float*)d_in[5];
    const float* b2  = (const float*)d_in[6];
    const float* Wfc = (const float*)d_in[7];
    const float* bfc = (const float*)d_in[8];
    const int*   src = (const int*)d_in[9];
    const int*   dst = (const int*)d_in[10];
    const int*   gid = (const int*)d_in[11];

    const int N  = in_sizes[11];          // 100000
    const int E  = in_sizes[9];           // 1600000
    const int K1 = in_sizes[0] / N;       // 67
    const int NC = in_sizes[8];           // 18
    const int G  = out_size / NC;         // 256

    char* w = (char*)d_ws;
    auto alloc = [&](size_t bytes) { char* p = w; w += (bytes + 255) & ~(size_t)255; return p; };
    unsigned int*   hb     = (unsigned int*)alloc((size_t)N * (LDA1 / 2) * 4);
    unsigned int*   agg1b  = (unsigned int*)alloc((size_t)N * (LDA1 / 2) * 4);
    unsigned short* x1b    = (unsigned short*)alloc((size_t)N * OW * 2);
    unsigned short* agg2b  = (unsigned short*)alloc((size_t)N * OW * 2);
    int*            rowptr = (int*)alloc((size_t)(N + 1) * 4);
    int*            cnt    = (int*)alloc((size_t)N * 4);
    int*            csr    = (int*)alloc((size_t)E * 4);
    int*            rank   = (int*)alloc((size_t)E * 4);
    int*            bsum   = (int*)alloc(1024 * 4);
    unsigned short* Bb1    = (unsigned short*)alloc((size_t)2 * 3 * 16 * 64 * 8 * 2);
    unsigned short* Bb2    = (unsigned short*)alloc((size_t)2 * 8 * 16 * 64 * 8 * 2);

    float* out = (float*)d_out;
    const int nb = (N + 1023) / 1024;

    // fused prep: h->bf16, pack W1/W2, count dst + per-edge rank
    hipMemsetAsync(cnt, 0, (size_t)N * sizeof(int), stream);
    prep_kernel<<<2048, 256, 0, stream>>>(h, hb, N, K1, W1s, W1n, Bb1, W2s, W2n, Bb2,
                                          dst, cnt, rank, E);

    // CSR scan + atomic-free fill
    scan_blocksum<<<nb, 1024, 0, stream>>>(cnt, bsum, N);
    scan_offsets<<<1, 128, 0, stream>>>(bsum, nb);
    scan_write<<<nb, 1024, 0, stream>>>(cnt, bsum, rowptr, N);
    fill_kernel<<<2048, 256, 0, stream>>>(src, dst, rank, rowptr, csr, E);

    const int gemm_grid = (N + 127) / 128;

    // layer 1  (KT_HALF=3, CHUNK=3 -> 2 chunks, 48 KB LDS)
    gather_mean_pad<<<4096, 256, 0, stream>>>(hb, rowptr, csr, agg1b, N);
    sage_mfma<3, 3><<<gemm_grid, 512, 0, stream>>>((const unsigned short*)hb,
                                                   (const unsigned short*)agg1b, LDA1,
                                                   Bb1, b1, x1b, N);

    // layer 2: column-split gather (two half passes), then in-place GEMM
    // (KT_HALF=8, CHUNK=4 -> 4 chunks, 64 KB LDS)
    gather_mean256_half<<<4096, 256, 0, stream>>>((const unsigned int*)x1b, rowptr, csr,
                                                  (unsigned int*)agg2b, N, 0);
    gather_mean256_half<<<4096, 256, 0, stream>>>((const unsigned int*)x1b, rowptr, csr,
                                                  (unsigned int*)agg2b, N, 1);
    sage_mfma<8, 4><<<gemm_grid, 512, 0, stream>>>(x1b, agg2b, OW, Bb2, b2, x1b, N);

    // per-graph mean pool + classifier
    pool_fc_kernel<<<G, 256, 0, stream>>>(x1b, gid, Wfc, bfc, out, N, NC);
}

// Round 11
// 426.494 us; speedup vs baseline: 1.3175x; 1.0362x over previous
//
#include <hip/hip_runtime.h>

#define WAVE 64
#define OW 256    // hidden width
#define LDA1 96   // padded layer-1 K (67 -> 96, zero pad)
#define NCHUNK 64 // edge chunks for the counting sort
#define PBITS 15  // 32768 bins per LDS part (packed 2x16-bit in 64 KB)
#define PBINS (1 << PBITS)
#define NPART 4   // ceil(100000 / 32768)

typedef short bf16x8 __attribute__((ext_vector_type(8)));
typedef float f32x4  __attribute__((ext_vector_type(4)));

__device__ __forceinline__ unsigned short f2bf(float f) {   // RNE fp32 -> bf16
    unsigned int u = __float_as_uint(f);
    u = (u + 0x7FFF + ((u >> 16) & 1)) >> 16;
    return (unsigned short)u;
}
__device__ __forceinline__ float bf2f(unsigned short u) {
    return __uint_as_float(((unsigned int)u) << 16);
}
__device__ __forceinline__ float bflo(unsigned int u) { return __uint_as_float(u << 16); }
__device__ __forceinline__ float bfhi(unsigned int u) { return __uint_as_float(u & 0xFFFF0000u); }
__device__ __forceinline__ unsigned int packbf(float lo, float hi) {
    return (unsigned int)f2bf(lo) | ((unsigned int)f2bf(hi) << 16);
}
__device__ __forceinline__ float lrelu(float x) { return x > 0.0f ? x : 0.01f * x; }

// ---------------- prep: h->bf16 padded + weight pre-pack (no atomics) ----------------

__device__ __forceinline__ void pack_b_body(const float* __restrict__ Ws,
                                            const float* __restrict__ Wn,
                                            unsigned short* __restrict__ Bb,
                                            int KHALF, int KT_HALF, int idx) {
    int e  = idx & 7;
    int l  = (idx >> 3) & 63;
    int nt = (idx >> 9) & 15;
    int kt = idx >> 13;
    int n  = nt * 16 + (l & 15);
    int kh = (kt < KT_HALF ? kt : kt - KT_HALF) * 32 + (l >> 4) * 8 + e;
    const float* W = (kt < KT_HALF) ? Ws : Wn;
    float v = (kh < KHALF) ? W[(size_t)kh * OW + n] : 0.0f;
    Bb[idx] = f2bf(v);
}

__global__ void prep_kernel(const float* __restrict__ h, unsigned int* __restrict__ hb,
                            int N, int K,
                            const float* __restrict__ W1s, const float* __restrict__ W1n,
                            unsigned short* __restrict__ Bb1,
                            const float* __restrict__ W2s, const float* __restrict__ W2n,
                            unsigned short* __restrict__ Bb2) {
    const int tid = blockIdx.x * blockDim.x + threadIdx.x;
    const int nth = gridDim.x * blockDim.x;

    const int tot_h = N * (LDA1 / 2);
    for (int i = tid; i < tot_h; i += nth) {
        int row = i / (LDA1 / 2);
        int c   = (i - row * (LDA1 / 2)) * 2;
        float v0 = (c     < K) ? h[(size_t)row * K + c]     : 0.0f;
        float v1 = (c + 1 < K) ? h[(size_t)row * K + c + 1] : 0.0f;
        hb[i] = packbf(v0, v1);
    }
    for (int i = tid; i < 2 * 3 * 16 * 64 * 8; i += nth)
        pack_b_body(W1s, W1n, Bb1, K, 3, i);
    for (int i = tid; i < 2 * 8 * 16 * 64 * 8; i += nth)
        pack_b_body(W2s, W2n, Bb2, OW, 8, i);
}

// ---------------- CSR build: LDS-privatized counting sort (no global atomics) ----------------

// block (c,p): count chunk c's dst in bin range [p*PBINS, ...) via packed LDS counters;
// rank_local[e] = returning LDS add; dump counters -> hist[c][bin]
__global__ __launch_bounds__(512) void hist_kernel(const int* __restrict__ dst, int E, int N,
                                                   int* __restrict__ hist,
                                                   unsigned short* __restrict__ rank_local) {
    __shared__ unsigned int lcnt[PBINS / 2];      // 64 KB, 2x16-bit packed
    const int c    = blockIdx.x / NPART;
    const int p    = blockIdx.x - c * NPART;
    const int base = p << PBITS;
    const int nb   = (N - base < PBINS) ? (N - base) : PBINS;
    if (nb <= 0) return;
    const int che = (E + NCHUNK - 1) / NCHUNK;
    const int beg = c * che;
    const int end = (beg + che < E) ? (beg + che) : E;

    for (int i = threadIdx.x; i < PBINS / 2; i += 512) lcnt[i] = 0;
    __syncthreads();

    for (int e = beg + (int)threadIdx.x; e < end; e += 512) {
        int d = dst[e] - base;
        if ((unsigned)d < (unsigned)nb) {
            unsigned int sh  = (d & 1) * 16;
            unsigned int old = atomicAdd(&lcnt[d >> 1], 1u << sh);
            rank_local[e] = (unsigned short)((old >> sh) & 0xFFFFu);
        }
    }
    __syncthreads();

    int* hrow = hist + (size_t)c * N + base;
    for (int i = threadIdx.x; i < nb; i += 512) {
        unsigned int v = lcnt[i >> 1];
        hrow[i] = (int)((v >> ((i & 1) * 16)) & 0xFFFFu);
    }
}

// per-bin exclusive prefix over chunks (coalesced per chunk-row); totals -> cnt
__global__ void chunk_scan_kernel(int* __restrict__ hist, int* __restrict__ cnt, int N) {
    int bin = blockIdx.x * blockDim.x + threadIdx.x;
    if (bin >= N) return;
    int s = 0;
#pragma unroll 8
    for (int c = 0; c < NCHUNK; ++c) {
        size_t idx = (size_t)c * N + bin;
        int t = hist[idx];
        hist[idx] = s;
        s += t;
    }
    cnt[bin] = s;
}

__global__ __launch_bounds__(1024) void scan_blocksum(const int* __restrict__ cnt,
                                                      int* __restrict__ bsum, int n) {
    __shared__ int s[1024];
    int i = blockIdx.x * 1024 + threadIdx.x;
    s[threadIdx.x] = (i < n) ? cnt[i] : 0;
    __syncthreads();
    for (int off = 512; off > 0; off >>= 1) {
        if (threadIdx.x < off) s[threadIdx.x] += s[threadIdx.x + off];
        __syncthreads();
    }
    if (threadIdx.x == 0) bsum[blockIdx.x] = s[0];
}

__global__ __launch_bounds__(128) void scan_offsets(int* __restrict__ bsum, int nb) {
    __shared__ int s[128];
    int v = (threadIdx.x < nb) ? bsum[threadIdx.x] : 0;
    s[threadIdx.x] = v;
    __syncthreads();
    for (int off = 1; off < 128; off <<= 1) {
        int t = (threadIdx.x >= off) ? s[threadIdx.x - off] : 0;
        __syncthreads();
        s[threadIdx.x] += t;
        __syncthreads();
    }
    if (threadIdx.x < nb) bsum[threadIdx.x] = s[threadIdx.x] - v;   // exclusive
}

__global__ __launch_bounds__(1024) void scan_write(const int* __restrict__ cnt,
                                                   const int* __restrict__ boff,
                                                   int* __restrict__ rowptr, int n) {
    __shared__ int s[1024];
    int i = blockIdx.x * 1024 + threadIdx.x;
    int v = (i < n) ? cnt[i] : 0;
    s[threadIdx.x] = v;
    __syncthreads();
    for (int off = 1; off < 1024; off <<= 1) {
        int t = (threadIdx.x >= off) ? s[threadIdx.x - off] : 0;
        __syncthreads();
        s[threadIdx.x] += t;
        __syncthreads();
    }
    if (i < n) rowptr[i + 1] = boff[blockIdx.x] + s[threadIdx.x];
    if (i == 0) rowptr[0] = 0;
}

// atomic-free fill: pos = rowptr[dst] + hist[chunk][dst] + rank_local
__global__ void fill_kernel(const int* __restrict__ src, const int* __restrict__ dst,
                            const unsigned short* __restrict__ rank_local,
                            const int* __restrict__ rowptr, const int* __restrict__ hist,
                            int* __restrict__ csr, int E, int N) {
    const int che = (E + NCHUNK - 1) / NCHUNK;
    const int tid = blockIdx.x * blockDim.x + threadIdx.x;
    const int nth = gridDim.x * blockDim.x;
    for (int e = tid; e < E; e += nth) {
        int d = dst[e];
        int c = e / che;
        int pos = rowptr[d] + hist[(size_t)c * N + d] + (int)rank_local[e];
        csr[pos] = src[e];
    }
}

// ---------------- gathers (neighbor MEAN, atomic-free) ----------------

// layer-2 gather, COLUMN-SPLIT: one pass covers 128 of 256 cols (half-row = 256 B).
__global__ void gather_mean256_half(const unsigned int* __restrict__ feat,
                                    const int* __restrict__ rowptr, const int* __restrict__ csr,
                                    unsigned int* __restrict__ aggm, int N, int colhalf) {
    const int lane = threadIdx.x & (WAVE - 1);
    const int grp  = lane >> 4;          // 0..3
    const int sub  = lane & 15;          // uint4 slot within half-row
    const int cb   = colhalf * 64;       // uint offset of column half
    int wave = (blockIdx.x * blockDim.x + threadIdx.x) / WAVE;
    int nw   = (gridDim.x * blockDim.x) / WAVE;

    for (int v = wave; v < N; v += nw) {
        const int beg = rowptr[v], deg = rowptr[v + 1] - beg;
        float l0 = 0.f, h0 = 0.f, l1 = 0.f, h1 = 0.f,
              l2 = 0.f, h2 = 0.f, l3 = 0.f, h3 = 0.f;

        const int noct = deg >> 3;           // each iter consumes 8 edges (4 grp x 2)
        for (int i = 0; i < noct; ++i) {
            int e0 = csr[beg + 8 * i + grp];
            int e1 = csr[beg + 8 * i + 4 + grp];
            uint4 x0 = *(const uint4*)(feat + (size_t)e0 * 128 + cb + sub * 4);
            uint4 x1 = *(const uint4*)(feat + (size_t)e1 * 128 + cb + sub * 4);
            l0 += bflo(x0.x) + bflo(x1.x); h0 += bfhi(x0.x) + bfhi(x1.x);
            l1 += bflo(x0.y) + bflo(x1.y); h1 += bfhi(x0.y) + bfhi(x1.y);
            l2 += bflo(x0.z) + bflo(x1.z); h2 += bfhi(x0.z) + bfhi(x1.z);
            l3 += bflo(x0.w) + bflo(x1.w); h3 += bfhi(x0.w) + bfhi(x1.w);
        }
        for (int e = (noct << 3) + grp; e < deg; e += 4) {   // tail, per-group
            int s = csr[beg + e];
            uint4 x = *(const uint4*)(feat + (size_t)s * 128 + cb + sub * 4);
            l0 += bflo(x.x); h0 += bfhi(x.x);
            l1 += bflo(x.y); h1 += bfhi(x.y);
            l2 += bflo(x.z); h2 += bfhi(x.z);
            l3 += bflo(x.w); h3 += bfhi(x.w);
        }
        // combine the 4 groups (xor-16 then xor-32)
        l0 += __shfl_xor(l0, 16); l0 += __shfl_xor(l0, 32);
        h0 += __shfl_xor(h0, 16); h0 += __shfl_xor(h0, 32);
        l1 += __shfl_xor(l1, 16); l1 += __shfl_xor(l1, 32);
        h1 += __shfl_xor(h1, 16); h1 += __shfl_xor(h1, 32);
        l2 += __shfl_xor(l2, 16); l2 += __shfl_xor(l2, 32);
        h2 += __shfl_xor(h2, 16); h2 += __shfl_xor(h2, 32);
        l3 += __shfl_xor(l3, 16); l3 += __shfl_xor(l3, 32);
        h3 += __shfl_xor(h3, 16); h3 += __shfl_xor(h3, 32);

        if (grp == 0) {
            float inv = 1.0f / fmaxf((float)deg, 1.0f);
            uint4 o;
            o.x = packbf(l0 * inv, h0 * inv);
            o.y = packbf(l1 * inv, h1 * inv);
            o.z = packbf(l2 * inv, h2 * inv);
            o.w = packbf(l3 * inv, h3 * inv);
            *(uint4*)(aggm + (size_t)v * 128 + cb + sub * 4) = o;
        }
    }
}

// layer-1 gather: rows of 96 bf16 (192 B = 48 uints); split-half wave, uint2/lane
__global__ void gather_mean_pad(const unsigned int* __restrict__ feat,
                                const int* __restrict__ rowptr, const int* __restrict__ csr,
                                unsigned int* __restrict__ aggm, int N) {
    const int lane = threadIdx.x & (WAVE - 1);
    const int half = lane >> 5;
    const int sub  = lane & 31;
    const bool act = sub < 24;
    int wave = (blockIdx.x * blockDim.x + threadIdx.x) / WAVE;
    int nw   = (gridDim.x * blockDim.x) / WAVE;

    for (int v = wave; v < N; v += nw) {
        const int beg = rowptr[v], deg = rowptr[v + 1] - beg;
        const int npairs = deg >> 1;
        float l0 = 0.f, h0 = 0.f, l1 = 0.f, h1 = 0.f;

        int p = 0;
        for (; p + 3 < npairs; p += 4) {
            int i0 = csr[beg + 2 * (p + 0) + half];
            int i1 = csr[beg + 2 * (p + 1) + half];
            int i2 = csr[beg + 2 * (p + 2) + half];
            int i3 = csr[beg + 2 * (p + 3) + half];
            if (act) {
                uint2 x0 = *(const uint2*)(feat + (size_t)i0 * 48 + sub * 2);
                uint2 x1 = *(const uint2*)(feat + (size_t)i1 * 48 + sub * 2);
                uint2 x2 = *(const uint2*)(feat + (size_t)i2 * 48 + sub * 2);
                uint2 x3 = *(const uint2*)(feat + (size_t)i3 * 48 + sub * 2);
                l0 += bflo(x0.x) + bflo(x1.x) + bflo(x2.x) + bflo(x3.x);
                h0 += bfhi(x0.x) + bfhi(x1.x) + bfhi(x2.x) + bfhi(x3.x);
                l1 += bflo(x0.y) + bflo(x1.y) + bflo(x2.y) + bflo(x3.y);
                h1 += bfhi(x0.y) + bfhi(x1.y) + bfhi(x2.y) + bfhi(x3.y);
            }
        }
        for (; p < npairs; ++p) {
            int i0 = csr[beg + 2 * p + half];
            if (act) {
                uint2 x0 = *(const uint2*)(feat + (size_t)i0 * 48 + sub * 2);
                l0 += bflo(x0.x); h0 += bfhi(x0.x);
                l1 += bflo(x0.y); h1 += bfhi(x0.y);
            }
        }
        if ((deg & 1) && half == 0) {
            int i0 = csr[beg + deg - 1];
            if (act) {
                uint2 x0 = *(const uint2*)(feat + (size_t)i0 * 48 + sub * 2);
                l0 += bflo(x0.x); h0 += bfhi(x0.x);
                l1 += bflo(x0.y); h1 += bfhi(x0.y);
            }
        }
        l0 += __shfl_xor(l0, 32); h0 += __shfl_xor(h0, 32);
        l1 += __shfl_xor(l1, 32); h1 += __shfl_xor(h1, 32);

        if (half == 0 && act) {
            float inv = 1.0f / fmaxf((float)deg, 1.0f);
            uint2 o;
            o.x = packbf(l0 * inv, h0 * inv);
            o.y = packbf(l1 * inv, h1 * inv);
            *(uint2*)(aggm + (size_t)v * 48 + sub * 2) = o;
        }
    }
}

// ---------------- MFMA SAGE GEMM (LDS-staged B, register-prefetched A) ----------------
template<int KT_HALF, int CHUNK>
__global__ __launch_bounds__(512) void sage_mfma(
    const unsigned short* __restrict__ Hs, const unsigned short* __restrict__ Hn, int lda,
    const unsigned short* __restrict__ Bb, const float* __restrict__ bias,
    unsigned short* __restrict__ outb, int M)
{
    constexpr int NT    = 2 * KT_HALF;
    constexpr int NCH   = NT / CHUNK;
    constexpr int CELEM = CHUNK * 16 * 64;           // bf16x8 elems per chunk
    constexpr int CPT   = CELEM / 512;               // per-thread stage count
    __shared__ bf16x8 Bs[CELEM];                     // CHUNK=4 -> 64 KB

    const int t    = threadIdx.x;
    const int lane = t & 63, wid = t >> 6;
    const int wm   = wid >> 1, wn = wid & 1;
    const int brow = blockIdx.x * 128;
    const int lrow = lane & 15, kblk = lane >> 4;

    const int r0 = brow + wm * 32 + lrow;
    const int r1 = r0 + 16;
    const int r0c = (r0 < M) ? r0 : (M - 1);
    const int r1c = (r1 < M) ? r1 : (M - 1);

    f32x4 acc[2][8];
#pragma unroll
    for (int rt = 0; rt < 2; ++rt)
#pragma unroll
        for (int ct = 0; ct < 8; ++ct) acc[rt][ct] = (f32x4)0.0f;

    for (int ch = 0; ch < NCH; ++ch) {
        bf16x8 a0[CHUNK], a1[CHUNK];
#pragma unroll
        for (int k = 0; k < CHUNK; ++k) {
            int kt = ch * CHUNK + k;
            bool self = kt < KT_HALF;
            int kh = (self ? kt : kt - KT_HALF) * 32 + kblk * 8;
            const unsigned short* srcp = self ? Hs : Hn;
            a0[k] = *(const bf16x8*)(srcp + (size_t)r0c * lda + kh);
            a1[k] = *(const bf16x8*)(srcp + (size_t)r1c * lda + kh);
        }
        const bf16x8* gB = (const bf16x8*)Bb + (size_t)ch * CELEM;
        bf16x8 tmp[CPT];
#pragma unroll
        for (int i = 0; i < CPT; ++i) tmp[i] = gB[i * 512 + t];
        __syncthreads();
#pragma unroll
        for (int i = 0; i < CPT; ++i) Bs[i * 512 + t] = tmp[i];
        __syncthreads();
#pragma unroll
        for (int k = 0; k < CHUNK; ++k) {
            const bf16x8* bp = &Bs[(k * 16 + wn * 8) * 64 + lane];
#pragma unroll
            for (int ct = 0; ct < 8; ++ct) {
                bf16x8 b = bp[ct * 64];
                acc[0][ct] = __builtin_amdgcn_mfma_f32_16x16x32_bf16(a0[k], b, acc[0][ct], 0, 0, 0);
                acc[1][ct] = __builtin_amdgcn_mfma_f32_16x16x32_bf16(a1[k], b, acc[1][ct], 0, 0, 0);
            }
        }
    }

    // D layout: col=lane&15, row=(lane>>4)*4+j
#pragma unroll
    for (int rt = 0; rt < 2; ++rt) {
        int rbase = brow + wm * 32 + rt * 16 + kblk * 4;
#pragma unroll
        for (int ct = 0; ct < 8; ++ct) {
            int col = wn * 128 + ct * 16 + lrow;
            float vb = bias[col];
#pragma unroll
            for (int j = 0; j < 4; ++j) {
                int row = rbase + j;
                if (row < M)
                    outb[(size_t)row * OW + col] = f2bf(lrelu(acc[rt][ct][j] + vb));
            }
        }
    }
}

// ---------------- per-graph mean pool + FC (graph_ids sorted) ----------------

__global__ __launch_bounds__(256) void pool_fc_kernel(
    const unsigned short* __restrict__ x, const int* __restrict__ gid,
    const float* __restrict__ Wfc, const float* __restrict__ bfc,
    float* __restrict__ out, int N, int C)
{
    int g = blockIdx.x;
    int lo = 0, hi = N;
    while (lo < hi) { int m = (lo + hi) >> 1; if (gid[m] < g) lo = m + 1; else hi = m; }
    int beg = lo;
    hi = N;
    while (lo < hi) { int m = (lo + hi) >> 1; if (gid[m] <= g) lo = m + 1; else hi = m; }
    int end = lo;

    __shared__ float hg[OW];
    int c = threadIdx.x;
    float s0 = 0.f, s1 = 0.f, s2 = 0.f, s3 = 0.f;
    int r = beg;
    for (; r + 3 < end; r += 4) {
        s0 += bf2f(x[(size_t)(r + 0) * OW + c]);
        s1 += bf2f(x[(size_t)(r + 1) * OW + c]);
        s2 += bf2f(x[(size_t)(r + 2) * OW + c]);
        s3 += bf2f(x[(size_t)(r + 3) * OW + c]);
    }
    for (; r < end; ++r) s0 += bf2f(x[(size_t)r * OW + c]);
    float s = (s0 + s1) + (s2 + s3);
    float inv = (end > beg) ? 1.0f / (float)(end - beg) : 0.0f;
    hg[c] = s * inv;
    __syncthreads();

    if (c < C) {
        float a = bfc[c];
        for (int k = 0; k < OW; ++k)
            a = fmaf(hg[k], Wfc[(size_t)k * C + c], a);
        out[(size_t)g * C + c] = a;
    }
}

extern "C" void kernel_launch(void* const* d_in, const int* in_sizes, int n_in,
                              void* d_out, int out_size, void* d_ws, size_t ws_size,
                              hipStream_t stream) {
    const float* h   = (const float*)d_in[0];
    const float* W1s = (const float*)d_in[1];
    const float* W1n = (const float*)d_in[2];
    const float* b1  = (const float*)d_in[3];
    const float* W2s = (const float*)d_in[4];
    const float* W2n = (const float*)d_in[5];
    const float* b2  = (const float*)d_in[6];
    const float* Wfc = (const float*)d_in[7];
    const float* bfc = (const float*)d_in[8];
    const int*   src = (const int*)d_in[9];
    const int*   dst = (const int*)d_in[10];
    const int*   gid = (const int*)d_in[11];

    const int N  = in_sizes[11];          // 100000
    const int E  = in_sizes[9];           // 1600000
    const int K1 = in_sizes[0] / N;       // 67
    const int NC = in_sizes[8];           // 18
    const int G  = out_size / NC;         // 256

    char* w = (char*)d_ws;
    auto alloc = [&](size_t bytes) { char* p = w; w += (bytes + 255) & ~(size_t)255; return p; };
    unsigned int*   hb     = (unsigned int*)alloc((size_t)N * (LDA1 / 2) * 4);
    unsigned int*   agg1b  = (unsigned int*)alloc((size_t)N * (LDA1 / 2) * 4);
    unsigned short* x1b    = (unsigned short*)alloc((size_t)N * OW * 2);
    unsigned short* agg2b  = (unsigned short*)alloc((size_t)N * OW * 2);
    int*            rowptr = (int*)alloc((size_t)(N + 1) * 4);
    int*            cnt    = (int*)alloc((size_t)N * 4);
    int*            csr    = (int*)alloc((size_t)E * 4);
    unsigned short* rankl  = (unsigned short*)alloc((size_t)E * 2);
    int*            hist   = (int*)alloc((size_t)NCHUNK * N * 4);
    int*            bsum   = (int*)alloc(1024 * 4);
    unsigned short* Bb1    = (unsigned short*)alloc((size_t)2 * 3 * 16 * 64 * 8 * 2);
    unsigned short* Bb2    = (unsigned short*)alloc((size_t)2 * 8 * 16 * 64 * 8 * 2);

    float* out = (float*)d_out;
    const int nb = (N + 1023) / 1024;

    // CSR build: LDS counting sort (no global atomics, no memsets needed)
    hist_kernel<<<NCHUNK * NPART, 512, 0, stream>>>(dst, E, N, hist, rankl);
    chunk_scan_kernel<<<(N + 255) / 256, 256, 0, stream>>>(hist, cnt, N);
    scan_blocksum<<<nb, 1024, 0, stream>>>(cnt, bsum, N);
    scan_offsets<<<1, 128, 0, stream>>>(bsum, nb);
    scan_write<<<nb, 1024, 0, stream>>>(cnt, bsum, rowptr, N);
    fill_kernel<<<2048, 256, 0, stream>>>(src, dst, rankl, rowptr, hist, csr, E, N);

    // prep: h->bf16 + weight packs (pure BW)
    prep_kernel<<<2048, 256, 0, stream>>>(h, hb, N, K1, W1s, W1n, Bb1, W2s, W2n, Bb2);

    const int gemm_grid = (N + 127) / 128;

    // layer 1  (KT_HALF=3, CHUNK=3 -> 2 chunks, 48 KB LDS)
    gather_mean_pad<<<4096, 256, 0, stream>>>(hb, rowptr, csr, agg1b, N);
    sage_mfma<3, 3><<<gemm_grid, 512, 0, stream>>>((const unsigned short*)hb,
                                                   (const unsigned short*)agg1b, LDA1,
                                                   Bb1, b1, x1b, N);

    // layer 2: column-split gather (two half passes), then in-place GEMM
    gather_mean256_half<<<4096, 256, 0, stream>>>((const unsigned int*)x1b, rowptr, csr,
                                                  (unsigned int*)agg2b, N, 0);
    gather_mean256_half<<<4096, 256, 0, stream>>>((const unsigned int*)x1b, rowptr, csr,
                                                  (unsigned int*)agg2b, N, 1);
    sage_mfma<8, 4><<<gemm_grid, 512, 0, stream>>>(x1b, agg2b, OW, Bb2, b2, x1b, N);

    // per-graph mean pool + classifier
    pool_fc_kernel<<<G, 256, 0, stream>>>(x1b, gid, Wfc, bfc, out, N, NC);
}

// Round 12
// 424.496 us; speedup vs baseline: 1.3237x; 1.0047x over previous
//
#include <hip/hip_runtime.h>

#define WAVE 64
#define OW 256    // hidden width
#define LDA1 96   // padded layer-1 K (67 -> 96, zero pad)
#define NCHUNK 64 // edge chunks for the counting sort
#define PBITS 15  // 32768 bins per LDS part (packed 2x16-bit in 64 KB)
#define PBINS (1 << PBITS)
#define NPART 4   // ceil(100000 / 32768)

typedef short bf16x8 __attribute__((ext_vector_type(8)));
typedef float f32x4  __attribute__((ext_vector_type(4)));

__device__ __forceinline__ unsigned short f2bf(float f) {   // RNE fp32 -> bf16
    unsigned int u = __float_as_uint(f);
    u = (u + 0x7FFF + ((u >> 16) & 1)) >> 16;
    return (unsigned short)u;
}
__device__ __forceinline__ float bf2f(unsigned short u) {
    return __uint_as_float(((unsigned int)u) << 16);
}
__device__ __forceinline__ float bflo(unsigned int u) { return __uint_as_float(u << 16); }
__device__ __forceinline__ float bfhi(unsigned int u) { return __uint_as_float(u & 0xFFFF0000u); }
__device__ __forceinline__ unsigned int packbf(float lo, float hi) {
    return (unsigned int)f2bf(lo) | ((unsigned int)f2bf(hi) << 16);
}
__device__ __forceinline__ float lrelu(float x) { return x > 0.0f ? x : 0.01f * x; }

// ---------------- prep: h->bf16 padded + weight pre-pack (no atomics) ----------------

__device__ __forceinline__ void pack_b_body(const float* __restrict__ Ws,
                                            const float* __restrict__ Wn,
                                            unsigned short* __restrict__ Bb,
                                            int KHALF, int KT_HALF, int idx) {
    int e  = idx & 7;
    int l  = (idx >> 3) & 63;
    int nt = (idx >> 9) & 15;
    int kt = idx >> 13;
    int n  = nt * 16 + (l & 15);
    int kh = (kt < KT_HALF ? kt : kt - KT_HALF) * 32 + (l >> 4) * 8 + e;
    const float* W = (kt < KT_HALF) ? Ws : Wn;
    float v = (kh < KHALF) ? W[(size_t)kh * OW + n] : 0.0f;
    Bb[idx] = f2bf(v);
}

__global__ void prep_kernel(const float* __restrict__ h, unsigned int* __restrict__ hb,
                            int N, int K,
                            const float* __restrict__ W1s, const float* __restrict__ W1n,
                            unsigned short* __restrict__ Bb1,
                            const float* __restrict__ W2s, const float* __restrict__ W2n,
                            unsigned short* __restrict__ Bb2) {
    const int tid = blockIdx.x * blockDim.x + threadIdx.x;
    const int nth = gridDim.x * blockDim.x;

    const int tot_h = N * (LDA1 / 2);
    for (int i = tid; i < tot_h; i += nth) {
        int row = i / (LDA1 / 2);
        int c   = (i - row * (LDA1 / 2)) * 2;
        float v0 = (c     < K) ? h[(size_t)row * K + c]     : 0.0f;
        float v1 = (c + 1 < K) ? h[(size_t)row * K + c + 1] : 0.0f;
        hb[i] = packbf(v0, v1);
    }
    for (int i = tid; i < 2 * 3 * 16 * 64 * 8; i += nth)
        pack_b_body(W1s, W1n, Bb1, K, 3, i);
    for (int i = tid; i < 2 * 8 * 16 * 64 * 8; i += nth)
        pack_b_body(W2s, W2n, Bb2, OW, 8, i);
}

// ---------------- CSR build: LDS-privatized counting sort (no global atomics) ----------------

__global__ __launch_bounds__(512) void hist_kernel(const int* __restrict__ dst, int E, int N,
                                                   int* __restrict__ hist,
                                                   unsigned short* __restrict__ rank_local) {
    __shared__ unsigned int lcnt[PBINS / 2];      // 64 KB, 2x16-bit packed
    const int c    = blockIdx.x / NPART;
    const int p    = blockIdx.x - c * NPART;
    const int base = p << PBITS;
    const int nb   = (N - base < PBINS) ? (N - base) : PBINS;
    if (nb <= 0) return;
    const int che = (E + NCHUNK - 1) / NCHUNK;
    const int beg = c * che;
    const int end = (beg + che < E) ? (beg + che) : E;

    for (int i = threadIdx.x; i < PBINS / 2; i += 512) lcnt[i] = 0;
    __syncthreads();

    for (int e = beg + (int)threadIdx.x; e < end; e += 512) {
        int d = dst[e] - base;
        if ((unsigned)d < (unsigned)nb) {
            unsigned int sh  = (d & 1) * 16;
            unsigned int old = atomicAdd(&lcnt[d >> 1], 1u << sh);
            rank_local[e] = (unsigned short)((old >> sh) & 0xFFFFu);
        }
    }
    __syncthreads();

    int* hrow = hist + (size_t)c * N + base;
    for (int i = threadIdx.x; i < nb; i += 512) {
        unsigned int v = lcnt[i >> 1];
        hrow[i] = (int)((v >> ((i & 1) * 16)) & 0xFFFFu);
    }
}

__global__ void chunk_scan_kernel(int* __restrict__ hist, int* __restrict__ cnt, int N) {
    int bin = blockIdx.x * blockDim.x + threadIdx.x;
    if (bin >= N) return;
    int s = 0;
#pragma unroll 8
    for (int c = 0; c < NCHUNK; ++c) {
        size_t idx = (size_t)c * N + bin;
        int t = hist[idx];
        hist[idx] = s;
        s += t;
    }
    cnt[bin] = s;
}

__global__ __launch_bounds__(1024) void scan_blocksum(const int* __restrict__ cnt,
                                                      int* __restrict__ bsum, int n) {
    __shared__ int s[1024];
    int i = blockIdx.x * 1024 + threadIdx.x;
    s[threadIdx.x] = (i < n) ? cnt[i] : 0;
    __syncthreads();
    for (int off = 512; off > 0; off >>= 1) {
        if (threadIdx.x < off) s[threadIdx.x] += s[threadIdx.x + off];
        __syncthreads();
    }
    if (threadIdx.x == 0) bsum[blockIdx.x] = s[0];
}

__global__ __launch_bounds__(128) void scan_offsets(int* __restrict__ bsum, int nb) {
    __shared__ int s[128];
    int v = (threadIdx.x < nb) ? bsum[threadIdx.x] : 0;
    s[threadIdx.x] = v;
    __syncthreads();
    for (int off = 1; off < 128; off <<= 1) {
        int t = (threadIdx.x >= off) ? s[threadIdx.x - off] : 0;
        __syncthreads();
        s[threadIdx.x] += t;
        __syncthreads();
    }
    if (threadIdx.x < nb) bsum[threadIdx.x] = s[threadIdx.x] - v;   // exclusive
}

__global__ __launch_bounds__(1024) void scan_write(const int* __restrict__ cnt,
                                                   const int* __restrict__ boff,
                                                   int* __restrict__ rowptr, int n) {
    __shared__ int s[1024];
    int i = blockIdx.x * 1024 + threadIdx.x;
    int v = (i < n) ? cnt[i] : 0;
    s[threadIdx.x] = v;
    __syncthreads();
    for (int off = 1; off < 1024; off <<= 1) {
        int t = (threadIdx.x >= off) ? s[threadIdx.x - off] : 0;
        __syncthreads();
        s[threadIdx.x] += t;
        __syncthreads();
    }
    if (i < n) rowptr[i + 1] = boff[blockIdx.x] + s[threadIdx.x];
    if (i == 0) rowptr[0] = 0;
}

// atomic-free fill: pos = rowptr[dst] + hist[chunk][dst] + rank_local
__global__ void fill_kernel(const int* __restrict__ src, const int* __restrict__ dst,
                            const unsigned short* __restrict__ rank_local,
                            const int* __restrict__ rowptr, const int* __restrict__ hist,
                            int* __restrict__ csr, int E, int N) {
    const int che = (E + NCHUNK - 1) / NCHUNK;
    const int tid = blockIdx.x * blockDim.x + threadIdx.x;
    const int nth = gridDim.x * blockDim.x;
    for (int e = tid; e < E; e += nth) {
        int d = dst[e];
        int c = e / che;
        int pos = rowptr[d] + hist[(size_t)c * N + d] + (int)rank_local[e];
        csr[pos] = src[e];
    }
}

// ---------------- gathers (neighbor MEAN, atomic-free) ----------------

__global__ void gather_mean256_half(const unsigned int* __restrict__ feat,
                                    const int* __restrict__ rowptr, const int* __restrict__ csr,
                                    unsigned int* __restrict__ aggm, int N, int colhalf) {
    const int lane = threadIdx.x & (WAVE - 1);
    const int grp  = lane >> 4;          // 0..3
    const int sub  = lane & 15;          // uint4 slot within half-row
    const int cb   = colhalf * 64;       // uint offset of column half
    int wave = (blockIdx.x * blockDim.x + threadIdx.x) / WAVE;
    int nw   = (gridDim.x * blockDim.x) / WAVE;

    for (int v = wave; v < N; v += nw) {
        const int beg = rowptr[v], deg = rowptr[v + 1] - beg;
        float l0 = 0.f, h0 = 0.f, l1 = 0.f, h1 = 0.f,
              l2 = 0.f, h2 = 0.f, l3 = 0.f, h3 = 0.f;

        const int noct = deg >> 3;
        for (int i = 0; i < noct; ++i) {
            int e0 = csr[beg + 8 * i + grp];
            int e1 = csr[beg + 8 * i + 4 + grp];
            uint4 x0 = *(const uint4*)(feat + (size_t)e0 * 128 + cb + sub * 4);
            uint4 x1 = *(const uint4*)(feat + (size_t)e1 * 128 + cb + sub * 4);
            l0 += bflo(x0.x) + bflo(x1.x); h0 += bfhi(x0.x) + bfhi(x1.x);
            l1 += bflo(x0.y) + bflo(x1.y); h1 += bfhi(x0.y) + bfhi(x1.y);
            l2 += bflo(x0.z) + bflo(x1.z); h2 += bfhi(x0.z) + bfhi(x1.z);
            l3 += bflo(x0.w) + bflo(x1.w); h3 += bfhi(x0.w) + bfhi(x1.w);
        }
        for (int e = (noct << 3) + grp; e < deg; e += 4) {
            int s = csr[beg + e];
            uint4 x = *(const uint4*)(feat + (size_t)s * 128 + cb + sub * 4);
            l0 += bflo(x.x); h0 += bfhi(x.x);
            l1 += bflo(x.y); h1 += bfhi(x.y);
            l2 += bflo(x.z); h2 += bfhi(x.z);
            l3 += bflo(x.w); h3 += bfhi(x.w);
        }
        l0 += __shfl_xor(l0, 16); l0 += __shfl_xor(l0, 32);
        h0 += __shfl_xor(h0, 16); h0 += __shfl_xor(h0, 32);
        l1 += __shfl_xor(l1, 16); l1 += __shfl_xor(l1, 32);
        h1 += __shfl_xor(h1, 16); h1 += __shfl_xor(h1, 32);
        l2 += __shfl_xor(l2, 16); l2 += __shfl_xor(l2, 32);
        h2 += __shfl_xor(h2, 16); h2 += __shfl_xor(h2, 32);
        l3 += __shfl_xor(l3, 16); l3 += __shfl_xor(l3, 32);
        h3 += __shfl_xor(h3, 16); h3 += __shfl_xor(h3, 32);

        if (grp == 0) {
            float inv = 1.0f / fmaxf((float)deg, 1.0f);
            uint4 o;
            o.x = packbf(l0 * inv, h0 * inv);
            o.y = packbf(l1 * inv, h1 * inv);
            o.z = packbf(l2 * inv, h2 * inv);
            o.w = packbf(l3 * inv, h3 * inv);
            *(uint4*)(aggm + (size_t)v * 128 + cb + sub * 4) = o;
        }
    }
}

__global__ void gather_mean_pad(const unsigned int* __restrict__ feat,
                                const int* __restrict__ rowptr, const int* __restrict__ csr,
                                unsigned int* __restrict__ aggm, int N) {
    const int lane = threadIdx.x & (WAVE - 1);
    const int half = lane >> 5;
    const int sub  = lane & 31;
    const bool act = sub < 24;
    int wave = (blockIdx.x * blockDim.x + threadIdx.x) / WAVE;
    int nw   = (gridDim.x * blockDim.x) / WAVE;

    for (int v = wave; v < N; v += nw) {
        const int beg = rowptr[v], deg = rowptr[v + 1] - beg;
        const int npairs = deg >> 1;
        float l0 = 0.f, h0 = 0.f, l1 = 0.f, h1 = 0.f;

        int p = 0;
        for (; p + 3 < npairs; p += 4) {
            int i0 = csr[beg + 2 * (p + 0) + half];
            int i1 = csr[beg + 2 * (p + 1) + half];
            int i2 = csr[beg + 2 * (p + 2) + half];
            int i3 = csr[beg + 2 * (p + 3) + half];
            if (act) {
                uint2 x0 = *(const uint2*)(feat + (size_t)i0 * 48 + sub * 2);
                uint2 x1 = *(const uint2*)(feat + (size_t)i1 * 48 + sub * 2);
                uint2 x2 = *(const uint2*)(feat + (size_t)i2 * 48 + sub * 2);
                uint2 x3 = *(const uint2*)(feat + (size_t)i3 * 48 + sub * 2);
                l0 += bflo(x0.x) + bflo(x1.x) + bflo(x2.x) + bflo(x3.x);
                h0 += bfhi(x0.x) + bfhi(x1.x) + bfhi(x2.x) + bfhi(x3.x);
                l1 += bflo(x0.y) + bflo(x1.y) + bflo(x2.y) + bflo(x3.y);
                h1 += bfhi(x0.y) + bfhi(x1.y) + bfhi(x2.y) + bfhi(x3.y);
            }
        }
        for (; p < npairs; ++p) {
            int i0 = csr[beg + 2 * p + half];
            if (act) {
                uint2 x0 = *(const uint2*)(feat + (size_t)i0 * 48 + sub * 2);
                l0 += bflo(x0.x); h0 += bfhi(x0.x);
                l1 += bflo(x0.y); h1 += bfhi(x0.y);
            }
        }
        if ((deg & 1) && half == 0) {
            int i0 = csr[beg + deg - 1];
            if (act) {
                uint2 x0 = *(const uint2*)(feat + (size_t)i0 * 48 + sub * 2);
                l0 += bflo(x0.x); h0 += bfhi(x0.x);
                l1 += bflo(x0.y); h1 += bfhi(x0.y);
            }
        }
        l0 += __shfl_xor(l0, 32); h0 += __shfl_xor(h0, 32);
        l1 += __shfl_xor(l1, 32); h1 += __shfl_xor(h1, 32);

        if (half == 0 && act) {
            float inv = 1.0f / fmaxf((float)deg, 1.0f);
            uint2 o;
            o.x = packbf(l0 * inv, h0 * inv);
            o.y = packbf(l1 * inv, h1 * inv);
            *(uint2*)(aggm + (size_t)v * 48 + sub * 2) = o;
        }
    }
}

// ---------------- MFMA SAGE GEMM (256 thr / 64-row tile, 32 KB LDS B-chunks) ----------------
// 4 waves = 2M x 2N; per wave 32 rows x 128 cols = 2x8 mfma_16x16x32 accs.
// CHUNK=2 -> 32 KB LDS -> ~4-5 blocks/CU for latency cover. Rows block-owned -> in-place ok.
template<int KT_HALF, int CHUNK>
__global__ __launch_bounds__(256) void sage_mfma(
    const unsigned short* __restrict__ Hs, const unsigned short* __restrict__ Hn, int lda,
    const unsigned short* __restrict__ Bb, const float* __restrict__ bias,
    unsigned short* __restrict__ outb, int M)
{
    constexpr int NT    = 2 * KT_HALF;
    constexpr int NCH   = NT / CHUNK;
    constexpr int CELEM = CHUNK * 16 * 64;           // bf16x8 elems per chunk
    constexpr int CPT   = CELEM / 256;               // per-thread stage count
    __shared__ bf16x8 Bs[CELEM];                     // CHUNK=2 -> 32 KB

    const int t    = threadIdx.x;
    const int lane = t & 63, wid = t >> 6;
    const int wm   = wid >> 1, wn = wid & 1;
    const int brow = blockIdx.x * 64;
    const int lrow = lane & 15, kblk = lane >> 4;

    const int r0 = brow + wm * 32 + lrow;
    const int r1 = r0 + 16;
    const int r0c = (r0 < M) ? r0 : (M - 1);
    const int r1c = (r1 < M) ? r1 : (M - 1);

    f32x4 acc[2][8];
#pragma unroll
    for (int rt = 0; rt < 2; ++rt)
#pragma unroll
        for (int ct = 0; ct < 8; ++ct) acc[rt][ct] = (f32x4)0.0f;

    for (int ch = 0; ch < NCH; ++ch) {
        // A register prefetch for this chunk
        bf16x8 a0[CHUNK], a1[CHUNK];
#pragma unroll
        for (int k = 0; k < CHUNK; ++k) {
            int kt = ch * CHUNK + k;
            bool self = kt < KT_HALF;
            int kh = (self ? kt : kt - KT_HALF) * 32 + kblk * 8;
            const unsigned short* srcp = self ? Hs : Hn;
            a0[k] = *(const bf16x8*)(srcp + (size_t)r0c * lda + kh);
            a1[k] = *(const bf16x8*)(srcp + (size_t)r1c * lda + kh);
        }
        // B chunk stage: global -> regs -> LDS (coalesced both sides)
        const bf16x8* gB = (const bf16x8*)Bb + (size_t)ch * CELEM;
        bf16x8 tmp[CPT];
#pragma unroll
        for (int i = 0; i < CPT; ++i) tmp[i] = gB[i * 256 + t];
        __syncthreads();                 // previous chunk's reads complete
#pragma unroll
        for (int i = 0; i < CPT; ++i) Bs[i * 256 + t] = tmp[i];
        __syncthreads();                 // chunk visible to all waves
        // compute
#pragma unroll
        for (int k = 0; k < CHUNK; ++k) {
            const bf16x8* bp = &Bs[(k * 16 + wn * 8) * 64 + lane];
#pragma unroll
            for (int ct = 0; ct < 8; ++ct) {
                bf16x8 b = bp[ct * 64];
                acc[0][ct] = __builtin_amdgcn_mfma_f32_16x16x32_bf16(a0[k], b, acc[0][ct], 0, 0, 0);
                acc[1][ct] = __builtin_amdgcn_mfma_f32_16x16x32_bf16(a1[k], b, acc[1][ct], 0, 0, 0);
            }
        }
    }

    // D layout: col=lane&15, row=(lane>>4)*4+j
#pragma unroll
    for (int rt = 0; rt < 2; ++rt) {
        int rbase = brow + wm * 32 + rt * 16 + kblk * 4;
#pragma unroll
        for (int ct = 0; ct < 8; ++ct) {
            int col = wn * 128 + ct * 16 + lrow;
            float vb = bias[col];
#pragma unroll
            for (int j = 0; j < 4; ++j) {
                int row = rbase + j;
                if (row < M)
                    outb[(size_t)row * OW + col] = f2bf(lrelu(acc[rt][ct][j] + vb));
            }
        }
    }
}

// ---------------- per-graph mean pool + FC (graph_ids sorted) ----------------

__global__ __launch_bounds__(256) void pool_fc_kernel(
    const unsigned short* __restrict__ x, const int* __restrict__ gid,
    const float* __restrict__ Wfc, const float* __restrict__ bfc,
    float* __restrict__ out, int N, int C)
{
    int g = blockIdx.x;
    int lo = 0, hi = N;
    while (lo < hi) { int m = (lo + hi) >> 1; if (gid[m] < g) lo = m + 1; else hi = m; }
    int beg = lo;
    hi = N;
    while (lo < hi) { int m = (lo + hi) >> 1; if (gid[m] <= g) lo = m + 1; else hi = m; }
    int end = lo;

    __shared__ float hg[OW];
    int c = threadIdx.x;
    float s0 = 0.f, s1 = 0.f, s2 = 0.f, s3 = 0.f;
    int r = beg;
    for (; r + 3 < end; r += 4) {
        s0 += bf2f(x[(size_t)(r + 0) * OW + c]);
        s1 += bf2f(x[(size_t)(r + 1) * OW + c]);
        s2 += bf2f(x[(size_t)(r + 2) * OW + c]);
        s3 += bf2f(x[(size_t)(r + 3) * OW + c]);
    }
    for (; r < end; ++r) s0 += bf2f(x[(size_t)r * OW + c]);
    float s = (s0 + s1) + (s2 + s3);
    float inv = (end > beg) ? 1.0f / (float)(end - beg) : 0.0f;
    hg[c] = s * inv;
    __syncthreads();

    if (c < C) {
        float a = bfc[c];
        for (int k = 0; k < OW; ++k)
            a = fmaf(hg[k], Wfc[(size_t)k * C + c], a);
        out[(size_t)g * C + c] = a;
    }
}

extern "C" void kernel_launch(void* const* d_in, const int* in_sizes, int n_in,
                              void* d_out, int out_size, void* d_ws, size_t ws_size,
                              hipStream_t stream) {
    const float* h   = (const float*)d_in[0];
    const float* W1s = (const float*)d_in[1];
    const float* W1n = (const float*)d_in[2];
    const float* b1  = (const float*)d_in[3];
    const float* W2s = (const float*)d_in[4];
    const float* W2n = (const float*)d_in[5];
    const float* b2  = (const float*)d_in[6];
    const float* Wfc = (const float*)d_in[7];
    const float* bfc = (const float*)d_in[8];
    const int*   src = (const int*)d_in[9];
    const int*   dst = (const int*)d_in[10];
    const int*   gid = (const int*)d_in[11];

    const int N  = in_sizes[11];          // 100000
    const int E  = in_sizes[9];           // 1600000
    const int K1 = in_sizes[0] / N;       // 67
    const int NC = in_sizes[8];           // 18
    const int G  = out_size / NC;         // 256

    char* w = (char*)d_ws;
    auto alloc = [&](size_t bytes) { char* p = w; w += (bytes + 255) & ~(size_t)255; return p; };
    unsigned int*   hb     = (unsigned int*)alloc((size_t)N * (LDA1 / 2) * 4);
    unsigned int*   agg1b  = (unsigned int*)alloc((size_t)N * (LDA1 / 2) * 4);
    unsigned short* x1b    = (unsigned short*)alloc((size_t)N * OW * 2);
    unsigned short* agg2b  = (unsigned short*)alloc((size_t)N * OW * 2);
    int*            rowptr = (int*)alloc((size_t)(N + 1) * 4);
    int*            cnt    = (int*)alloc((size_t)N * 4);
    int*            csr    = (int*)alloc((size_t)E * 4);
    unsigned short* rankl  = (unsigned short*)alloc((size_t)E * 2);
    int*            hist   = (int*)alloc((size_t)NCHUNK * N * 4);
    int*            bsum   = (int*)alloc(1024 * 4);
    unsigned short* Bb1    = (unsigned short*)alloc((size_t)2 * 3 * 16 * 64 * 8 * 2);
    unsigned short* Bb2    = (unsigned short*)alloc((size_t)2 * 8 * 16 * 64 * 8 * 2);

    float* out = (float*)d_out;
    const int nb = (N + 1023) / 1024;

    // CSR build: LDS counting sort (no global atomics, no memsets needed)
    hist_kernel<<<NCHUNK * NPART, 512, 0, stream>>>(dst, E, N, hist, rankl);
    chunk_scan_kernel<<<(N + 255) / 256, 256, 0, stream>>>(hist, cnt, N);
    scan_blocksum<<<nb, 1024, 0, stream>>>(cnt, bsum, N);
    scan_offsets<<<1, 128, 0, stream>>>(bsum, nb);
    scan_write<<<nb, 1024, 0, stream>>>(cnt, bsum, rowptr, N);
    fill_kernel<<<2048, 256, 0, stream>>>(src, dst, rankl, rowptr, hist, csr, E, N);

    // prep: h->bf16 + weight packs (pure BW)
    prep_kernel<<<2048, 256, 0, stream>>>(h, hb, N, K1, W1s, W1n, Bb1, W2s, W2n, Bb2);

    const int gemm_grid = (N + 63) / 64;

    // layer 1  (KT_HALF=3, CHUNK=2 -> 3 chunks, 32 KB LDS)
    gather_mean_pad<<<4096, 256, 0, stream>>>(hb, rowptr, csr, agg1b, N);
    sage_mfma<3, 2><<<gemm_grid, 256, 0, stream>>>((const unsigned short*)hb,
                                                   (const unsigned short*)agg1b, LDA1,
                                                   Bb1, b1, x1b, N);

    // layer 2: column-split gather (two half passes), then in-place GEMM
    // (KT_HALF=8, CHUNK=2 -> 8 chunks, 32 KB LDS)
    gather_mean256_half<<<4096, 256, 0, stream>>>((const unsigned int*)x1b, rowptr, csr,
                                                  (unsigned int*)agg2b, N, 0);
    gather_mean256_half<<<4096, 256, 0, stream>>>((const unsigned int*)x1b, rowptr, csr,
                                                  (unsigned int*)agg2b, N, 1);
    sage_mfma<8, 2><<<gemm_grid, 256, 0, stream>>>(x1b, agg2b, OW, Bb2, b2, x1b, N);

    // per-graph mean pool + classifier
    pool_fc_kernel<<<G, 256, 0, stream>>>(x1b, gid, Wfc, bfc, out, N, NC);
}